// Round 3
// baseline (487.671 us; speedup 1.0000x reference)
//
#include <hip/hip_runtime.h>
#include <hip/hip_bf16.h>
#include <math.h>

#define Bv 4
#define Sv 2048
#define Dv 1024
#define Hv 16
#define HD 64
#define NEGV (-1.0e9f)

typedef __attribute__((ext_vector_type(8))) short bf16x8;   // 8 bf16 = 16 B
typedef __attribute__((ext_vector_type(4))) short s16x4;    // 4 bf16 = 8 B
typedef __attribute__((ext_vector_type(4))) float f32x4;    // 16x16 MFMA C/D
typedef __attribute__((ext_vector_type(16))) float f32x16;  // 32x32 MFMA C/D

__device__ __forceinline__ short f2bf(float f) {
    union { __hip_bfloat16 h; short s; } u;
    u.h = __float2bfloat16(f);
    return u.s;
}

// Pack two f32 -> one u32 of 2x bf16 (a -> low 16, b -> high 16). Library
// semantics (no asm): correctness-first; revisit v_cvt_pk_bf16_f32 later.
__device__ __forceinline__ unsigned pkbf(float a, float b) {
    union { __hip_bfloat162 h2; unsigned u; } un;
    un.h2 = __float22bfloat162_rn(make_float2(a, b));
    return un.u;
}

#if __has_builtin(__builtin_amdgcn_exp2f)
#define EXP2F(x) __builtin_amdgcn_exp2f(x)
#else
#define EXP2F(x) __expf((x) * 0.6931471805599453f)
#endif

__device__ __forceinline__ void glds16(const void* g, void* l) {
    __builtin_amdgcn_global_load_lds(
        (const __attribute__((address_space(1))) void*)g,
        (__attribute__((address_space(3))) void*)l, 16, 0, 0);
}

// ---------------------------------------------------------------------------
// fp32 -> bf16 bulk convert. 8 elems/thread. n must be /2048.
// ---------------------------------------------------------------------------
__global__ __launch_bounds__(256) void cvt_bf16(const float* __restrict__ X,
                                                unsigned short* __restrict__ Y) {
    const size_t i = ((size_t)blockIdx.x * 256 + threadIdx.x) * 8;
    const float4 a = *(const float4*)&X[i];
    const float4 b = *(const float4*)&X[i + 4];
    bf16x8 o = {f2bf(a.x), f2bf(a.y), f2bf(a.z), f2bf(a.w),
                f2bf(b.x), f2bf(b.y), f2bf(b.z), f2bf(b.w)};
    *(bf16x8*)&Y[i] = o;
}

// ---------------------------------------------------------------------------
// fp32 W [K=1024][N=1024] -> bf16 W^T [N][K]. Grid (16,16), 256 thr.
// ---------------------------------------------------------------------------
__global__ __launch_bounds__(256) void transpose_w(const float* __restrict__ W,
                                                   unsigned short* __restrict__ WT) {
    __shared__ float T[64][65];
    const int t = threadIdx.x;
    const int n0 = blockIdx.x * 64, k0 = blockIdx.y * 64;
    #pragma unroll
    for (int i = 0; i < 4; ++i) {
        const int k = (t >> 4) + 16 * i;
        const int nc = (t & 15) * 4;
        const float4 v = *(const float4*)&W[(size_t)(k0 + k) * 1024 + n0 + nc];
        T[k][nc + 0] = v.x; T[k][nc + 1] = v.y;
        T[k][nc + 2] = v.z; T[k][nc + 3] = v.w;
    }
    __syncthreads();
    const int n = t >> 2, kc = (t & 3) * 16;
    #pragma unroll
    for (int j4 = 0; j4 < 4; ++j4) {
        s16x4 o;
        #pragma unroll
        for (int jj = 0; jj < 4; ++jj) o[jj] = f2bf(T[kc + j4 * 4 + jj][n]);
        *(s16x4*)&WT[(size_t)(n0 + n) * 1024 + k0 + kc + j4 * 4] = o;
    }
}

// ---------------------------------------------------------------------------
// bf16 V [BH][S][64] -> V^T [BH][64][S]. Grid (S/64, nBH), 256 thr.
// ---------------------------------------------------------------------------
__global__ __launch_bounds__(256) void transpose_v(const unsigned short* __restrict__ Vin,
                                                   unsigned short* __restrict__ VT) {
    __shared__ unsigned short T[64][72];
    const int t = threadIdx.x;
    const int s0 = blockIdx.x * 64;
    const int bh = blockIdx.y;
    const size_t ib = (size_t)bh * Sv * 64;
    const size_t ob = (size_t)bh * 64 * Sv;
    {
        const int s = t >> 2, dc = (t & 3) * 16;
        const bf16x8 a = *(const bf16x8*)&Vin[ib + (size_t)(s0 + s) * 64 + dc];
        const bf16x8 b = *(const bf16x8*)&Vin[ib + (size_t)(s0 + s) * 64 + dc + 8];
        *(bf16x8*)&T[s][dc] = a;
        *(bf16x8*)&T[s][dc + 8] = b;
    }
    __syncthreads();
    const int dv = t >> 2, sc = (t & 3) * 16;
    #pragma unroll
    for (int j4 = 0; j4 < 4; ++j4) {
        s16x4 o;
        #pragma unroll
        for (int jj = 0; jj < 4; ++jj) o[jj] = (short)T[sc + j4 * 4 + jj][dv];
        *(s16x4*)&VT[ob + (size_t)dv * Sv + s0 + sc + j4 * 4] = o;
    }
}

// ---------------------------------------------------------------------------
// bf16 MFMA GEMM: C = X[MxK](bf16) @ W + bias, weights as bf16 W^T [N][K].
// 128x128 tile, BK=32, 256 thr = 4 waves (2x2), 4x4 16x16x32 MFMA per wave.
// Both operands staged via global_load_lds width-16 (m97 structure).
// PERM=1: C bf16 -> [B,H,S,64]. PERM=0: C fp32 row-major [M,N].
// ---------------------------------------------------------------------------
template <int PERM>
__global__ __launch_bounds__(256) void gemm_mfma(const unsigned short* __restrict__ X,
                                                 const unsigned short* __restrict__ WT,
                                                 const float* __restrict__ bias,
                                                 void* __restrict__ Cv,
                                                 int M, int N, int K) {
    __shared__ short As[128 * 32];
    __shared__ short Bs[128 * 32];

    const int t = threadIdx.x;
    const int lane = t & 63, w = t >> 6;
    const int l15 = lane & 15, quad = lane >> 4;
    const int m0 = blockIdx.y * 128, n0 = blockIdx.x * 128;
    const int wm = (w >> 1) * 64, wn = (w & 1) * 64;

    f32x4 acc[4][4];
    #pragma unroll
    for (int mi = 0; mi < 4; ++mi)
        #pragma unroll
        for (int ni = 0; ni < 4; ++ni) acc[mi][ni] = (f32x4){0.f, 0.f, 0.f, 0.f};

    const int srow = lane >> 2;          // 16 rows per seg
    const int skc = (lane & 3) * 8;      // 8 bf16 = 16 B per lane

    for (int k0 = 0; k0 < K; k0 += 32) {
        #pragma unroll
        for (int i = 0; i < 2; ++i) {
            const int seg = w * 2 + i;
            const int row = seg * 16 + srow;
            glds16(&WT[(size_t)(n0 + row) * K + k0 + skc], &Bs[seg * 512]);
            glds16(&X[(size_t)(m0 + row) * K + k0 + skc], &As[seg * 512]);
        }
        __syncthreads();

        bf16x8 afr[4], bfr[4];
        #pragma unroll
        for (int mi = 0; mi < 4; ++mi)
            afr[mi] = *(const bf16x8*)&As[(wm + mi * 16 + l15) * 32 + quad * 8];
        #pragma unroll
        for (int ni = 0; ni < 4; ++ni)
            bfr[ni] = *(const bf16x8*)&Bs[(wn + ni * 16 + l15) * 32 + quad * 8];
        #pragma unroll
        for (int mi = 0; mi < 4; ++mi)
            #pragma unroll
            for (int ni = 0; ni < 4; ++ni)
                acc[mi][ni] = __builtin_amdgcn_mfma_f32_16x16x32_bf16(
                    afr[mi], bfr[ni], acc[mi][ni], 0, 0, 0);
        __syncthreads();
    }

    // Epilogue. C/D: col = l15, row = quad*4 + r.
    #pragma unroll
    for (int mi = 0; mi < 4; ++mi) {
        #pragma unroll
        for (int ni = 0; ni < 4; ++ni) {
            const int col = n0 + wn + ni * 16 + l15;
            const float bsv = bias[col];
            #pragma unroll
            for (int r = 0; r < 4; ++r) {
                const int row = m0 + wm + mi * 16 + quad * 4 + r;
                const float vv = acc[mi][ni][r] + bsv;
                if constexpr (PERM == 0) {
                    ((float*)Cv)[(size_t)row * N + col] = vv;
                } else {
                    const int bb = row / Sv, s = row % Sv;
                    const int hh = col >> 6, d = col & 63;
                    ((unsigned short*)Cv)[((((size_t)bb * Hv + hh) * Sv + s) << 6) + d] =
                        (unsigned short)f2bf(vv);
                }
            }
        }
    }
}

// ---------------------------------------------------------------------------
// Flash attention, S^T form, no-max softmax, 128-q-row tiles, 32x32x16 MFMA.
// Grid (S/128, H, B), 256 thr = 4 waves; wave w owns q-rows [w*32, w*32+32).
// QK^T: A = K (m = kk), B = Q (n = qrow). C/D (m74): col=lane&31 -> qrow,
//   row=(reg&3)+8*(reg>>2)+4*hi -> kk, i.e. st[4g+i] <-> kk = 8g+4hi+i.
// PV with OWN-KK k-step decomposition (no cross-lane exchange!): define the
//   k-step's (hi,elem)->kk bijection to be what the lane ALREADY holds:
//     e<4  <-> kk = ks*16 + 4*hi + e
//     e>=4 <-> kk = ks*16 + 8 + 4*hi + (e-4)
//   A-frag = own p[8ks..8ks+7] packed pairwise; B-frag (V) = two b64 chunks
//   at bytes ks*32+8*hi and ks*32+16+8*hi. MFMA contracts element-wise with
//   identical maps on both operands => correct for any true HW k-layout.
// K/V tiles in LDS [64][64] bf16, XOR-swizzled (T2): byte ^= (row&7)<<4.
// T14 async-stage: next tile's K/V global-loaded into regs during compute.
// LDS = 2*8KB + 256 B = 16.6 KB.
// ---------------------------------------------------------------------------
__global__ __launch_bounds__(256, 4) void attn_mfma(const unsigned short* __restrict__ Q,
                                                    const unsigned short* __restrict__ Kg,
                                                    const unsigned short* __restrict__ VT,
                                                    const int* __restrict__ mask,
                                                    unsigned short* __restrict__ O) {
    __shared__ short Kl[64 * 64];    // [kk][d], swizzled
    __shared__ short Vl[64 * 64];    // [dv][kk], swizzled
    __shared__ float Mk[64];

    const int t = threadIdx.x;
    const int lane = t & 63, w = t >> 6;
    const int l31 = lane & 31, hi = lane >> 5;
    const int q0 = blockIdx.x * 128;
    const int h = blockIdx.y, b = blockIdx.z;
    const int bh = b * Hv + h;
    const size_t kvb = (size_t)bh * Sv * 64;
    const size_t vtb = (size_t)bh * 64 * Sv;
    const int fsw = (l31 & 7) << 4;          // fragment-read swizzle

    // Q B-fragments: lane holds Q[qrow = l31][d = j*16 + hi*8 .. +8].
    bf16x8 qf[4];
    {
        const unsigned short* Qb = Q + kvb + (size_t)(q0 + w * 32 + l31) * 64;
        #pragma unroll
        for (int j = 0; j < 4; ++j) qf[j] = *(const bf16x8*)&Qb[j * 16 + hi * 8];
    }

    float l_acc = 0.f;
    f32x16 oacc[2];
    #pragma unroll
    for (int d = 0; d < 2; ++d)
        #pragma unroll
        for (int i = 0; i < 16; ++i) oacc[d][i] = 0.f;

    // Staging: thread t writes row = t>>2, 2x16B at byte cols (t&3)*32 (+16),
    // XOR-swizzled by (row&7)<<4. Global source is linear.
    const int srow = t >> 2;
    const int ssw = (srow & 7) << 4;
    const int sc0 = ((t & 3) * 32) ^ ssw;
    const int sc1 = ((t & 3) * 32 + 16) ^ ssw;
    const unsigned short* Kst = Kg + kvb + (size_t)srow * 64 + (t & 3) * 16;
    const unsigned short* Vst = VT + vtb + (size_t)srow * Sv + (t & 3) * 16;
    const int* Mst = mask + (size_t)b * Sv;

    // Prologue: prefetch tile 0 into registers.
    bf16x8 kr0 = *(const bf16x8*)&Kst[0];
    bf16x8 kr1 = *(const bf16x8*)&Kst[8];
    bf16x8 vr0 = *(const bf16x8*)&Vst[0];
    bf16x8 vr1 = *(const bf16x8*)&Vst[8];
    int mreg = (t < 64) ? Mst[t] : 0;

    constexpr float CS = 0.18033688011112042f;   // 0.125 * log2(e)
    constexpr float CM = NEGV * 1.4426950408889634f;

    for (int k0 = 0; k0 < Sv; k0 += 64) {
        __syncthreads();                          // prev compute done with LDS
        *(bf16x8*)((char*)Kl + srow * 128 + sc0) = kr0;
        *(bf16x8*)((char*)Kl + srow * 128 + sc1) = kr1;
        *(bf16x8*)((char*)Vl + srow * 128 + sc0) = vr0;
        *(bf16x8*)((char*)Vl + srow * 128 + sc1) = vr1;
        if (t < 64) Mk[t] = CM * (float)mreg;
        __syncthreads();

        // T14: issue next tile's global loads now; retire during compute.
        if (k0 + 64 < Sv) {
            kr0 = *(const bf16x8*)&Kst[(size_t)(k0 + 64) * 64];
            kr1 = *(const bf16x8*)&Kst[(size_t)(k0 + 64) * 64 + 8];
            vr0 = *(const bf16x8*)&Vst[k0 + 64];
            vr1 = *(const bf16x8*)&Vst[k0 + 64 + 8];
            if (t < 64) mreg = Mst[k0 + 64 + t];
        }

        bf16x8 paf[2][2];   // [kb][ks] PV A-fragments (own-kk layout)
        #pragma unroll
        for (int kb = 0; kb < 2; ++kb) {
            // QK^T for this 32-kk block.
            f32x16 st;
            #pragma unroll
            for (int i = 0; i < 16; ++i) st[i] = 0.f;
            #pragma unroll
            for (int j = 0; j < 4; ++j) {
                const bf16x8 kf = *(const bf16x8*)((const char*)Kl +
                    (kb * 32 + l31) * 128 + ((j * 32 + hi * 16) ^ fsw));
                st = __builtin_amdgcn_mfma_f32_32x32x16_bf16(kf, qf[j], st, 0, 0, 0);
            }
            // Softmax (no-max): p[4g+i] for kk = kb*32 + 8g + 4hi + i.
            float p[16];
            #pragma unroll
            for (int g = 0; g < 4; ++g) {
                const float4 mk4 = *(const float4*)&Mk[kb * 32 + 8 * g + 4 * hi];
                const float e0 = EXP2F(__builtin_fmaf(st[4 * g + 0], CS, mk4.x));
                const float e1 = EXP2F(__builtin_fmaf(st[4 * g + 1], CS, mk4.y));
                const float e2 = EXP2F(__builtin_fmaf(st[4 * g + 2], CS, mk4.z));
                const float e3 = EXP2F(__builtin_fmaf(st[4 * g + 3], CS, mk4.w));
                p[4 * g + 0] = e0; p[4 * g + 1] = e1;
                p[4 * g + 2] = e2; p[4 * g + 3] = e3;
                l_acc += (e0 + e1) + (e2 + e3);
            }
            // Own-kk pack: paf[kb][ks] words = pk(p[8ks+2w], p[8ks+2w+1]).
            #pragma unroll
            for (int ks = 0; ks < 2; ++ks) {
                union { unsigned u[4]; bf16x8 v; } pu;
                #pragma unroll
                for (int wd = 0; wd < 4; ++wd)
                    pu.u[wd] = pkbf(p[8 * ks + 2 * wd], p[8 * ks + 2 * wd + 1]);
                paf[kb][ks] = pu.v;
            }
        }

        // O += P·V. kstep js (kk base js*16); B chunks at js*32+8hi, +16.
        #pragma unroll
        for (int db = 0; db < 2; ++db) {
            const char* vrow = (const char*)Vl + (db * 32 + l31) * 128;
            #pragma unroll
            for (int js = 0; js < 4; ++js) {
                const int bofs = js * 32 + hi * 8;
                union { s16x4 h[2]; bf16x8 v; } vu;
                vu.h[0] = *(const s16x4*)(vrow + (bofs ^ fsw));
                vu.h[1] = *(const s16x4*)(vrow + ((bofs + 16) ^ fsw));
                oacc[db] = __builtin_amdgcn_mfma_f32_32x32x16_bf16(
                    paf[js >> 1][js & 1], vu.v, oacc[db], 0, 0, 0);
            }
        }
    }

    // Row sums: lane holds partial for qrow = l31; combine hi halves.
    float l = l_acc + __shfl_xor(l_acc, 32);
    const float linv = 1.0f / l;
    // Output: D layout col = db*32 + l31 (dv), row = (r&3) + 8*(r>>2) + 4*hi.
    #pragma unroll
    for (int db = 0; db < 2; ++db) {
        #pragma unroll
        for (int r = 0; r < 16; ++r) {
            const int rowl = (r & 3) + 8 * (r >> 2) + 4 * hi;
            const float inv = __shfl(linv, rowl, 64);
            const size_t row = (size_t)b * Sv + q0 + w * 32 + rowl;
            O[row * (Hv * HD) + h * HD + db * 32 + l31] =
                (unsigned short)f2bf(oacc[db][r] * inv);
        }
    }
}

// ---------------------------------------------------------------------------
extern "C" void kernel_launch(void* const* d_in, const int* in_sizes, int n_in,
                              void* d_out, int out_size, void* d_ws, size_t ws_size,
                              hipStream_t stream) {
    const float* query = (const float*)d_in[0];
    const float* key   = (const float*)d_in[1];
    const float* value = (const float*)d_in[2];
    const int*   amask = (const int*)d_in[3];
    const float* wq = (const float*)d_in[4];
    const float* bq = (const float*)d_in[5];
    const float* wk = (const float*)d_in[6];
    const float* bk = (const float*)d_in[7];
    const float* wv = (const float*)d_in[8];
    const float* bv = (const float*)d_in[9];
    const float* wo = (const float*)d_in[10];
    const float* bo = (const float*)d_in[11];
    float* out = (float*)d_out;

    unsigned short* wsp = (unsigned short*)d_ws;
    dim3 bb(256), gt(16, 16);

    if (ws_size >= (size_t)64 * 1024 * 1024) {
        // ws: qb | kb | vb | ab (16 MB each, bf16 8M elems).
        const size_t PBQ = (size_t)Bv * Hv * Sv * HD;  // 8,388,608
        unsigned short* qb = wsp;
        unsigned short* kb = qb + PBQ;
        unsigned short* vb = kb + PBQ;
        unsigned short* ab = vb + PBQ;
        unsigned short* wt_kb = kb;                    // kb dead until K-GEMM
        unsigned short* wt_out = (unsigned short*)d_out;  // d_out dead until end
        unsigned short* wt_vb = vb;                    // vb dead after attn

        const int M = Bv * Sv;
        dim3 gg(8, M / 128), gc(M * 1024 / 2048);

        // V path: cvt(value)->ab ; V-GEMM ab->qb(temp) ; transpose qb->vb
        cvt_bf16<<<gc, bb, 0, stream>>>(value, ab);
        transpose_w<<<gt, bb, 0, stream>>>(wv, wt_kb);
        gemm_mfma<1><<<gg, bb, 0, stream>>>(ab, wt_kb, bv, qb, M, 1024, 1024);
        transpose_v<<<dim3(Sv / 64, Bv * Hv), bb, 0, stream>>>(qb, vb);

        // Q path (kb still dead)
        cvt_bf16<<<gc, bb, 0, stream>>>(query, ab);
        transpose_w<<<gt, bb, 0, stream>>>(wq, wt_kb);
        gemm_mfma<1><<<gg, bb, 0, stream>>>(ab, wt_kb, bq, qb, M, 1024, 1024);

        // K path (W^T scratch in d_out; kb is the GEMM target now)
        cvt_bf16<<<gc, bb, 0, stream>>>(key, ab);
        transpose_w<<<gt, bb, 0, stream>>>(wk, wt_out);
        gemm_mfma<1><<<gg, bb, 0, stream>>>(ab, wt_out, bk, kb, M, 1024, 1024);

        // Attention -> ab
        attn_mfma<<<dim3(Sv / 128, Hv, Bv), bb, 0, stream>>>(qb, kb, vb, amask, ab);

        // Output projection (W^T in dead vb; writes every element of d_out)
        transpose_w<<<gt, bb, 0, stream>>>(wo, wt_vb);
        gemm_mfma<0><<<gg, bb, 0, stream>>>(ab, wt_vb, bo, out, M, 1024, 1024);
    } else {
        // Per-batch fallback: qb|kb|vb|ab at 4 MB each = 16 MB.
        const size_t PQ = (size_t)Hv * Sv * HD;  // 2,097,152
        unsigned short* qb = wsp;
        unsigned short* kb = qb + PQ;
        unsigned short* vb = kb + PQ;
        unsigned short* ab = vb + PQ;
        const int M = Sv;
        dim3 gg(8, M / 128), gc(M * 1024 / 2048);
        for (int b = 0; b < Bv; ++b) {
            const size_t xoff = (size_t)b * Sv * Dv;
            unsigned short* wt_kb = kb;
            unsigned short* wt_out = (unsigned short*)(out + xoff);
            unsigned short* wt_vb = vb;

            cvt_bf16<<<gc, bb, 0, stream>>>(value + xoff, ab);
            transpose_w<<<gt, bb, 0, stream>>>(wv, wt_kb);
            gemm_mfma<1><<<gg, bb, 0, stream>>>(ab, wt_kb, bv, qb, M, 1024, 1024);
            transpose_v<<<dim3(Sv / 64, Hv), bb, 0, stream>>>(qb, vb);

            cvt_bf16<<<gc, bb, 0, stream>>>(query + xoff, ab);
            transpose_w<<<gt, bb, 0, stream>>>(wq, wt_kb);
            gemm_mfma<1><<<gg, bb, 0, stream>>>(ab, wt_kb, bq, qb, M, 1024, 1024);

            cvt_bf16<<<gc, bb, 0, stream>>>(key + xoff, ab);
            transpose_w<<<gt, bb, 0, stream>>>(wk, wt_out);
            gemm_mfma<1><<<gg, bb, 0, stream>>>(ab, wt_out, bk, kb, M, 1024, 1024);

            attn_mfma<<<dim3(Sv / 128, Hv, 1), bb, 0, stream>>>(qb, kb, vb,
                                                                amask + (size_t)b * Sv, ab);

            transpose_w<<<gt, bb, 0, stream>>>(wo, wt_vb);
            gemm_mfma<0><<<gg, bb, 0, stream>>>(ab, wt_vb, bo, out + xoff, M, 1024, 1024);
        }
    }
}

// Round 4
// 421.732 us; speedup vs baseline: 1.1564x; 1.1564x over previous
//
#include <hip/hip_runtime.h>
#include <hip/hip_bf16.h>
#include <math.h>

#define Bv 4
#define Sv 2048
#define Dv 1024
#define Hv 16
#define HD 64
#define NEGV (-1.0e9f)

typedef __attribute__((ext_vector_type(8))) short bf16x8;   // 8 bf16 = 16 B
typedef __attribute__((ext_vector_type(4))) short s16x4;    // 4 bf16 = 8 B
typedef __attribute__((ext_vector_type(4))) float f32x4;    // 16x16 MFMA C/D
typedef __attribute__((ext_vector_type(16))) float f32x16;  // 32x32 MFMA C/D

__device__ __forceinline__ short f2bf(float f) {
    union { __hip_bfloat16 h; short s; } u;
    u.h = __float2bfloat16(f);
    return u.s;
}

// Pack two f32 -> one u32 of 2x bf16 (a -> low 16, b -> high 16).
__device__ __forceinline__ unsigned pkbf(float a, float b) {
    union { __hip_bfloat162 h2; unsigned u; } un;
    un.h2 = __float22bfloat162_rn(make_float2(a, b));
    return un.u;
}

#if __has_builtin(__builtin_amdgcn_exp2f)
#define EXP2F(x) __builtin_amdgcn_exp2f(x)
#else
#define EXP2F(x) __expf((x) * 0.6931471805599453f)
#endif

__device__ __forceinline__ void glds16(const void* g, void* l) {
    __builtin_amdgcn_global_load_lds(
        (const __attribute__((address_space(1))) void*)g,
        (__attribute__((address_space(3))) void*)l, 16, 0, 0);
}

// ---------------------------------------------------------------------------
// fp32 -> bf16 bulk convert. 8 elems/thread. n must be /2048.
// ---------------------------------------------------------------------------
__global__ __launch_bounds__(256) void cvt_bf16(const float* __restrict__ X,
                                                unsigned short* __restrict__ Y) {
    const size_t i = ((size_t)blockIdx.x * 256 + threadIdx.x) * 8;
    const float4 a = *(const float4*)&X[i];
    const float4 b = *(const float4*)&X[i + 4];
    bf16x8 o = {f2bf(a.x), f2bf(a.y), f2bf(a.z), f2bf(a.w),
                f2bf(b.x), f2bf(b.y), f2bf(b.z), f2bf(b.w)};
    *(bf16x8*)&Y[i] = o;
}

// ---------------------------------------------------------------------------
// fp32 W [K=1024][N=1024] -> bf16 W^T [N][K]. Grid (16,16), 256 thr.
// ---------------------------------------------------------------------------
__global__ __launch_bounds__(256) void transpose_w(const float* __restrict__ W,
                                                   unsigned short* __restrict__ WT) {
    __shared__ float T[64][65];
    const int t = threadIdx.x;
    const int n0 = blockIdx.x * 64, k0 = blockIdx.y * 64;
    #pragma unroll
    for (int i = 0; i < 4; ++i) {
        const int k = (t >> 4) + 16 * i;
        const int nc = (t & 15) * 4;
        const float4 v = *(const float4*)&W[(size_t)(k0 + k) * 1024 + n0 + nc];
        T[k][nc + 0] = v.x; T[k][nc + 1] = v.y;
        T[k][nc + 2] = v.z; T[k][nc + 3] = v.w;
    }
    __syncthreads();
    const int n = t >> 2, kc = (t & 3) * 16;
    #pragma unroll
    for (int j4 = 0; j4 < 4; ++j4) {
        s16x4 o;
        #pragma unroll
        for (int jj = 0; jj < 4; ++jj) o[jj] = f2bf(T[kc + j4 * 4 + jj][n]);
        *(s16x4*)&WT[(size_t)(n0 + n) * 1024 + k0 + kc + j4 * 4] = o;
    }
}

// ---------------------------------------------------------------------------
// bf16 V [BH][S][64] -> V^T [BH][64][S]. Grid (S/64, nBH), 256 thr.
// ---------------------------------------------------------------------------
__global__ __launch_bounds__(256) void transpose_v(const unsigned short* __restrict__ Vin,
                                                   unsigned short* __restrict__ VT) {
    __shared__ unsigned short T[64][72];
    const int t = threadIdx.x;
    const int s0 = blockIdx.x * 64;
    const int bh = blockIdx.y;
    const size_t ib = (size_t)bh * Sv * 64;
    const size_t ob = (size_t)bh * 64 * Sv;
    {
        const int s = t >> 2, dc = (t & 3) * 16;
        const bf16x8 a = *(const bf16x8*)&Vin[ib + (size_t)(s0 + s) * 64 + dc];
        const bf16x8 b = *(const bf16x8*)&Vin[ib + (size_t)(s0 + s) * 64 + dc + 8];
        *(bf16x8*)&T[s][dc] = a;
        *(bf16x8*)&T[s][dc + 8] = b;
    }
    __syncthreads();
    const int dv = t >> 2, sc = (t & 3) * 16;
    #pragma unroll
    for (int j4 = 0; j4 < 4; ++j4) {
        s16x4 o;
        #pragma unroll
        for (int jj = 0; jj < 4; ++jj) o[jj] = (short)T[sc + j4 * 4 + jj][dv];
        *(s16x4*)&VT[ob + (size_t)dv * Sv + s0 + sc + j4 * 4] = o;
    }
}

// ---------------------------------------------------------------------------
// bf16 MFMA GEMM: C = X[MxK](bf16) @ W + bias, weights as bf16 W^T [N][K].
// 128x128 tile, BK=32, 256 thr = 4 waves (2x2), 4x4 16x16x32 MFMA per wave.
// Both operands staged via global_load_lds width-16 (m97 structure).
// PERM=1: C bf16 -> [B,H,S,64]. PERM=0: C fp32 row-major [M,N].
// ---------------------------------------------------------------------------
template <int PERM>
__global__ __launch_bounds__(256) void gemm_mfma(const unsigned short* __restrict__ X,
                                                 const unsigned short* __restrict__ WT,
                                                 const float* __restrict__ bias,
                                                 void* __restrict__ Cv,
                                                 int M, int N, int K) {
    __shared__ short As[128 * 32];
    __shared__ short Bs[128 * 32];

    const int t = threadIdx.x;
    const int lane = t & 63, w = t >> 6;
    const int l15 = lane & 15, quad = lane >> 4;
    const int m0 = blockIdx.y * 128, n0 = blockIdx.x * 128;
    const int wm = (w >> 1) * 64, wn = (w & 1) * 64;

    f32x4 acc[4][4];
    #pragma unroll
    for (int mi = 0; mi < 4; ++mi)
        #pragma unroll
        for (int ni = 0; ni < 4; ++ni) acc[mi][ni] = (f32x4){0.f, 0.f, 0.f, 0.f};

    const int srow = lane >> 2;          // 16 rows per seg
    const int skc = (lane & 3) * 8;      // 8 bf16 = 16 B per lane

    for (int k0 = 0; k0 < K; k0 += 32) {
        #pragma unroll
        for (int i = 0; i < 2; ++i) {
            const int seg = w * 2 + i;
            const int row = seg * 16 + srow;
            glds16(&WT[(size_t)(n0 + row) * K + k0 + skc], &Bs[seg * 512]);
            glds16(&X[(size_t)(m0 + row) * K + k0 + skc], &As[seg * 512]);
        }
        __syncthreads();

        bf16x8 afr[4], bfr[4];
        #pragma unroll
        for (int mi = 0; mi < 4; ++mi)
            afr[mi] = *(const bf16x8*)&As[(wm + mi * 16 + l15) * 32 + quad * 8];
        #pragma unroll
        for (int ni = 0; ni < 4; ++ni)
            bfr[ni] = *(const bf16x8*)&Bs[(wn + ni * 16 + l15) * 32 + quad * 8];
        #pragma unroll
        for (int mi = 0; mi < 4; ++mi)
            #pragma unroll
            for (int ni = 0; ni < 4; ++ni)
                acc[mi][ni] = __builtin_amdgcn_mfma_f32_16x16x32_bf16(
                    afr[mi], bfr[ni], acc[mi][ni], 0, 0, 0);
        __syncthreads();
    }

    // Epilogue. C/D: col = l15, row = quad*4 + r.
    #pragma unroll
    for (int mi = 0; mi < 4; ++mi) {
        #pragma unroll
        for (int ni = 0; ni < 4; ++ni) {
            const int col = n0 + wn + ni * 16 + l15;
            const float bsv = bias[col];
            #pragma unroll
            for (int r = 0; r < 4; ++r) {
                const int row = m0 + wm + mi * 16 + quad * 4 + r;
                const float vv = acc[mi][ni][r] + bsv;
                if constexpr (PERM == 0) {
                    ((float*)Cv)[(size_t)row * N + col] = vv;
                } else {
                    const int bb = row / Sv, s = row % Sv;
                    const int hh = col >> 6, d = col & 63;
                    ((unsigned short*)Cv)[((((size_t)bb * Hv + hh) * Sv + s) << 6) + d] =
                        (unsigned short)f2bf(vv);
                }
            }
        }
    }
}

// ---------------------------------------------------------------------------
// Flash attention, S^T form, no-max softmax, 128-q-row tiles, 32x32x16 MFMA.
// Grid (S/128, H, B), 256 thr = 4 waves; wave w owns q-rows [w*32, w*32+32).
// QK^T: A = K (m = kk), B = Q (n = qrow). C/D (m74): col=lane&31 -> qrow,
//   row=(reg&3)+8*(reg>>2)+4*hi -> kk, i.e. st[4g+i] <-> kk = 8g+4hi+i.
// PV with OWN-KK k-step decomposition (no cross-lane exchange): the k-step's
//   (hi,elem)->kk bijection is what the lane ALREADY holds; identical maps on
//   A (P) and B (V) operands => correct for any true HW k-layout.
// Per-32kk-block fused pipeline: QK^T -> pack (no p[] array) -> PV, so st and
//   paf never coexist across blocks: peak ~100 VGPR, NO SPILLS (R3 lesson:
//   launch_bounds(256,4) capped VGPR=64 -> 120 MB scratch traffic).
// K/V tiles in LDS [64][64] bf16, XOR-swizzled (T2): byte ^= (row&7)<<4.
// T14 async-stage: next tile's K/V global-loaded into regs during compute.
// LDS = 2*8KB + 256 B = 16.6 KB.
// ---------------------------------------------------------------------------
__global__ __launch_bounds__(256, 2) void attn_mfma(const unsigned short* __restrict__ Q,
                                                    const unsigned short* __restrict__ Kg,
                                                    const unsigned short* __restrict__ VT,
                                                    const int* __restrict__ mask,
                                                    unsigned short* __restrict__ O) {
    __shared__ short Kl[64 * 64];    // [kk][d], swizzled
    __shared__ short Vl[64 * 64];    // [dv][kk], swizzled
    __shared__ float Mk[64];

    const int t = threadIdx.x;
    const int lane = t & 63, w = t >> 6;
    const int l31 = lane & 31, hi = lane >> 5;
    const int q0 = blockIdx.x * 128;
    const int h = blockIdx.y, b = blockIdx.z;
    const int bh = b * Hv + h;
    const size_t kvb = (size_t)bh * Sv * 64;
    const size_t vtb = (size_t)bh * 64 * Sv;
    const int fsw = (l31 & 7) << 4;          // fragment-read swizzle

    // Q B-fragments: lane holds Q[qrow = l31][d = j*16 + hi*8 .. +8].
    bf16x8 qf[4];
    {
        const unsigned short* Qb = Q + kvb + (size_t)(q0 + w * 32 + l31) * 64;
        #pragma unroll
        for (int j = 0; j < 4; ++j) qf[j] = *(const bf16x8*)&Qb[j * 16 + hi * 8];
    }

    float l_acc = 0.f;
    f32x16 oacc[2];
    #pragma unroll
    for (int d = 0; d < 2; ++d)
        #pragma unroll
        for (int i = 0; i < 16; ++i) oacc[d][i] = 0.f;

    // Staging: thread t writes row = t>>2, 2x16B at byte cols (t&3)*32 (+16),
    // XOR-swizzled by (row&7)<<4. Global source is linear.
    const int srow = t >> 2;
    const int ssw = (srow & 7) << 4;
    const int sc0 = ((t & 3) * 32) ^ ssw;
    const int sc1 = ((t & 3) * 32 + 16) ^ ssw;
    const unsigned short* Kst = Kg + kvb + (size_t)srow * 64 + (t & 3) * 16;
    const unsigned short* Vst = VT + vtb + (size_t)srow * Sv + (t & 3) * 16;
    const int* Mst = mask + (size_t)b * Sv;

    // Prologue: prefetch tile 0 into registers.
    bf16x8 kr0 = *(const bf16x8*)&Kst[0];
    bf16x8 kr1 = *(const bf16x8*)&Kst[8];
    bf16x8 vr0 = *(const bf16x8*)&Vst[0];
    bf16x8 vr1 = *(const bf16x8*)&Vst[8];
    int mreg = (t < 64) ? Mst[t] : 0;

    constexpr float CS = 0.18033688011112042f;   // 0.125 * log2(e)
    constexpr float CM = NEGV * 1.4426950408889634f;

    for (int k0 = 0; k0 < Sv; k0 += 64) {
        __syncthreads();                          // prev compute done with LDS
        *(bf16x8*)((char*)Kl + srow * 128 + sc0) = kr0;
        *(bf16x8*)((char*)Kl + srow * 128 + sc1) = kr1;
        *(bf16x8*)((char*)Vl + srow * 128 + sc0) = vr0;
        *(bf16x8*)((char*)Vl + srow * 128 + sc1) = vr1;
        if (t < 64) Mk[t] = CM * (float)mreg;
        __syncthreads();

        // T14: issue next tile's global loads now; retire during compute.
        if (k0 + 64 < Sv) {
            kr0 = *(const bf16x8*)&Kst[(size_t)(k0 + 64) * 64];
            kr1 = *(const bf16x8*)&Kst[(size_t)(k0 + 64) * 64 + 8];
            vr0 = *(const bf16x8*)&Vst[k0 + 64];
            vr1 = *(const bf16x8*)&Vst[k0 + 64 + 8];
            if (t < 64) mreg = Mst[k0 + 64 + t];
        }

        #pragma unroll
        for (int kb = 0; kb < 2; ++kb) {
            // QK^T for this 32-kk block.
            f32x16 st;
            #pragma unroll
            for (int i = 0; i < 16; ++i) st[i] = 0.f;
            #pragma unroll
            for (int j = 0; j < 4; ++j) {
                const bf16x8 kf = *(const bf16x8*)((const char*)Kl +
                    (kb * 32 + l31) * 128 + ((j * 32 + hi * 16) ^ fsw));
                st = __builtin_amdgcn_mfma_f32_32x32x16_bf16(kf, qf[j], st, 0, 0, 0);
            }
            // Softmax + own-kk pack, fused (no p[] array; st dies here).
            bf16x8 paf2[2];
            #pragma unroll
            for (int ks = 0; ks < 2; ++ks) {
                union { unsigned u[4]; bf16x8 v; } pu;
                #pragma unroll
                for (int gg = 0; gg < 2; ++gg) {
                    const int g = 2 * ks + gg;
                    const float4 mk4 = *(const float4*)&Mk[kb * 32 + 8 * g + 4 * hi];
                    const float e0 = EXP2F(__builtin_fmaf(st[4 * g + 0], CS, mk4.x));
                    const float e1 = EXP2F(__builtin_fmaf(st[4 * g + 1], CS, mk4.y));
                    const float e2 = EXP2F(__builtin_fmaf(st[4 * g + 2], CS, mk4.z));
                    const float e3 = EXP2F(__builtin_fmaf(st[4 * g + 3], CS, mk4.w));
                    l_acc += (e0 + e1) + (e2 + e3);
                    pu.u[2 * gg + 0] = pkbf(e0, e1);
                    pu.u[2 * gg + 1] = pkbf(e2, e3);
                }
                paf2[ks] = pu.v;
            }
            // PV for this block's two k-steps (kk base kb*32 + ks*16).
            #pragma unroll
            for (int db = 0; db < 2; ++db) {
                const char* vrow = (const char*)Vl + (db * 32 + l31) * 128;
                #pragma unroll
                for (int ks = 0; ks < 2; ++ks) {
                    const int bofs = kb * 64 + ks * 32 + hi * 8;
                    union { s16x4 h[2]; bf16x8 v; } vu;
                    vu.h[0] = *(const s16x4*)(vrow + (bofs ^ fsw));
                    vu.h[1] = *(const s16x4*)(vrow + ((bofs + 16) ^ fsw));
                    oacc[db] = __builtin_amdgcn_mfma_f32_32x32x16_bf16(
                        paf2[ks], vu.v, oacc[db], 0, 0, 0);
                }
            }
        }
    }

    // Row sums: lane holds partial for qrow = l31; combine hi halves.
    float l = l_acc + __shfl_xor(l_acc, 32);
    const float linv = 1.0f / l;
    // Output: D layout col = db*32 + l31 (dv), row = (r&3) + 8*(r>>2) + 4*hi.
    #pragma unroll
    for (int db = 0; db < 2; ++db) {
        #pragma unroll
        for (int r = 0; r < 16; ++r) {
            const int rowl = (r & 3) + 8 * (r >> 2) + 4 * hi;
            const float inv = __shfl(linv, rowl, 64);
            const size_t row = (size_t)b * Sv + q0 + w * 32 + rowl;
            O[row * (Hv * HD) + h * HD + db * 32 + l31] =
                (unsigned short)f2bf(oacc[db][r] * inv);
        }
    }
}

// ---------------------------------------------------------------------------
extern "C" void kernel_launch(void* const* d_in, const int* in_sizes, int n_in,
                              void* d_out, int out_size, void* d_ws, size_t ws_size,
                              hipStream_t stream) {
    const float* query = (const float*)d_in[0];
    const float* key   = (const float*)d_in[1];
    const float* value = (const float*)d_in[2];
    const int*   amask = (const int*)d_in[3];
    const float* wq = (const float*)d_in[4];
    const float* bq = (const float*)d_in[5];
    const float* wk = (const float*)d_in[6];
    const float* bk = (const float*)d_in[7];
    const float* wv = (const float*)d_in[8];
    const float* bv = (const float*)d_in[9];
    const float* wo = (const float*)d_in[10];
    const float* bo = (const float*)d_in[11];
    float* out = (float*)d_out;

    unsigned short* wsp = (unsigned short*)d_ws;
    dim3 bb(256), gt(16, 16);

    if (ws_size >= (size_t)64 * 1024 * 1024) {
        // ws: qb | kb | vb | ab (16 MB each, bf16 8M elems).
        const size_t PBQ = (size_t)Bv * Hv * Sv * HD;  // 8,388,608
        unsigned short* qb = wsp;
        unsigned short* kb = qb + PBQ;
        unsigned short* vb = kb + PBQ;
        unsigned short* ab = vb + PBQ;
        unsigned short* wt_kb = kb;                    // kb dead until K-GEMM
        unsigned short* wt_out = (unsigned short*)d_out;  // d_out dead until end
        unsigned short* wt_vb = vb;                    // vb dead after attn

        const int M = Bv * Sv;
        dim3 gg(8, M / 128), gc(M * 1024 / 2048);

        // V path: cvt(value)->ab ; V-GEMM ab->qb(temp) ; transpose qb->vb
        cvt_bf16<<<gc, bb, 0, stream>>>(value, ab);
        transpose_w<<<gt, bb, 0, stream>>>(wv, wt_kb);
        gemm_mfma<1><<<gg, bb, 0, stream>>>(ab, wt_kb, bv, qb, M, 1024, 1024);
        transpose_v<<<dim3(Sv / 64, Bv * Hv), bb, 0, stream>>>(qb, vb);

        // Q path (kb still dead)
        cvt_bf16<<<gc, bb, 0, stream>>>(query, ab);
        transpose_w<<<gt, bb, 0, stream>>>(wq, wt_kb);
        gemm_mfma<1><<<gg, bb, 0, stream>>>(ab, wt_kb, bq, qb, M, 1024, 1024);

        // K path (W^T scratch in d_out; kb is the GEMM target now)
        cvt_bf16<<<gc, bb, 0, stream>>>(key, ab);
        transpose_w<<<gt, bb, 0, stream>>>(wk, wt_out);
        gemm_mfma<1><<<gg, bb, 0, stream>>>(ab, wt_out, bk, kb, M, 1024, 1024);

        // Attention -> ab
        attn_mfma<<<dim3(Sv / 128, Hv, Bv), bb, 0, stream>>>(qb, kb, vb, amask, ab);

        // Output projection (W^T in dead vb; writes every element of d_out)
        transpose_w<<<gt, bb, 0, stream>>>(wo, wt_vb);
        gemm_mfma<0><<<gg, bb, 0, stream>>>(ab, wt_vb, bo, out, M, 1024, 1024);
    } else {
        // Per-batch fallback: qb|kb|vb|ab at 4 MB each = 16 MB.
        const size_t PQ = (size_t)Hv * Sv * HD;  // 2,097,152
        unsigned short* qb = wsp;
        unsigned short* kb = qb + PQ;
        unsigned short* vb = kb + PQ;
        unsigned short* ab = vb + PQ;
        const int M = Sv;
        dim3 gg(8, M / 128), gc(M * 1024 / 2048);
        for (int b = 0; b < Bv; ++b) {
            const size_t xoff = (size_t)b * Sv * Dv;
            unsigned short* wt_kb = kb;
            unsigned short* wt_out = (unsigned short*)(out + xoff);
            unsigned short* wt_vb = vb;

            cvt_bf16<<<gc, bb, 0, stream>>>(value + xoff, ab);
            transpose_w<<<gt, bb, 0, stream>>>(wv, wt_kb);
            gemm_mfma<1><<<gg, bb, 0, stream>>>(ab, wt_kb, bv, qb, M, 1024, 1024);
            transpose_v<<<dim3(Sv / 64, Hv), bb, 0, stream>>>(qb, vb);

            cvt_bf16<<<gc, bb, 0, stream>>>(query + xoff, ab);
            transpose_w<<<gt, bb, 0, stream>>>(wq, wt_kb);
            gemm_mfma<1><<<gg, bb, 0, stream>>>(ab, wt_kb, bq, qb, M, 1024, 1024);

            cvt_bf16<<<gc, bb, 0, stream>>>(key + xoff, ab);
            transpose_w<<<gt, bb, 0, stream>>>(wk, wt_out);
            gemm_mfma<1><<<gg, bb, 0, stream>>>(ab, wt_out, bk, kb, M, 1024, 1024);

            attn_mfma<<<dim3(Sv / 128, Hv, 1), bb, 0, stream>>>(qb, kb, vb,
                                                                amask + (size_t)b * Sv, ab);

            transpose_w<<<gt, bb, 0, stream>>>(wo, wt_vb);
            gemm_mfma<0><<<gg, bb, 0, stream>>>(ab, wt_vb, bo, out + xoff, M, 1024, 1024);
        }
    }
}

// Round 5
// 418.458 us; speedup vs baseline: 1.1654x; 1.0078x over previous
//
#include <hip/hip_runtime.h>
#include <hip/hip_bf16.h>
#include <math.h>

#define Bv 4
#define Sv 2048
#define Dv 1024
#define Hv 16
#define HD 64
#define NEGV (-1.0e9f)

typedef __attribute__((ext_vector_type(8))) short bf16x8;   // 8 bf16 = 16 B
typedef __attribute__((ext_vector_type(4))) short s16x4;    // 4 bf16 = 8 B
typedef __attribute__((ext_vector_type(4))) float f32x4;    // 16x16 MFMA C/D
typedef __attribute__((ext_vector_type(16))) float f32x16;  // 32x32 MFMA C/D

__device__ __forceinline__ short f2bf(float f) {
    union { __hip_bfloat16 h; short s; } u;
    u.h = __float2bfloat16(f);
    return u.s;
}

// Pack two f32 -> one u32 of 2x bf16 (a -> low 16, b -> high 16).
__device__ __forceinline__ unsigned pkbf(float a, float b) {
    union { __hip_bfloat162 h2; unsigned u; } un;
    un.h2 = __float22bfloat162_rn(make_float2(a, b));
    return un.u;
}

#if __has_builtin(__builtin_amdgcn_exp2f)
#define EXP2F(x) __builtin_amdgcn_exp2f(x)
#else
#define EXP2F(x) __expf((x) * 0.6931471805599453f)
#endif

__device__ __forceinline__ void glds16(const void* g, void* l) {
    __builtin_amdgcn_global_load_lds(
        (const __attribute__((address_space(1))) void*)g,
        (__attribute__((address_space(3))) void*)l, 16, 0, 0);
}

// ---------------------------------------------------------------------------
// fp32 -> bf16 bulk convert. 8 elems/thread. n must be /2048.
// ---------------------------------------------------------------------------
__global__ __launch_bounds__(256) void cvt_bf16(const float* __restrict__ X,
                                                unsigned short* __restrict__ Y) {
    const size_t i = ((size_t)blockIdx.x * 256 + threadIdx.x) * 8;
    const float4 a = *(const float4*)&X[i];
    const float4 b = *(const float4*)&X[i + 4];
    bf16x8 o = {f2bf(a.x), f2bf(a.y), f2bf(a.z), f2bf(a.w),
                f2bf(b.x), f2bf(b.y), f2bf(b.z), f2bf(b.w)};
    *(bf16x8*)&Y[i] = o;
}

// ---------------------------------------------------------------------------
// fp32 W [K=1024][N=1024] -> bf16 W^T [N][K]. Grid (16,16), 256 thr.
// ---------------------------------------------------------------------------
__global__ __launch_bounds__(256) void transpose_w(const float* __restrict__ W,
                                                   unsigned short* __restrict__ WT) {
    __shared__ float T[64][65];
    const int t = threadIdx.x;
    const int n0 = blockIdx.x * 64, k0 = blockIdx.y * 64;
    #pragma unroll
    for (int i = 0; i < 4; ++i) {
        const int k = (t >> 4) + 16 * i;
        const int nc = (t & 15) * 4;
        const float4 v = *(const float4*)&W[(size_t)(k0 + k) * 1024 + n0 + nc];
        T[k][nc + 0] = v.x; T[k][nc + 1] = v.y;
        T[k][nc + 2] = v.z; T[k][nc + 3] = v.w;
    }
    __syncthreads();
    const int n = t >> 2, kc = (t & 3) * 16;
    #pragma unroll
    for (int j4 = 0; j4 < 4; ++j4) {
        s16x4 o;
        #pragma unroll
        for (int jj = 0; jj < 4; ++jj) o[jj] = f2bf(T[kc + j4 * 4 + jj][n]);
        *(s16x4*)&WT[(size_t)(n0 + n) * 1024 + k0 + kc + j4 * 4] = o;
    }
}

// ---------------------------------------------------------------------------
// bf16 V [BH][S][64] -> V^T [BH][64][S]. Grid (S/64, nBH), 256 thr.
// ---------------------------------------------------------------------------
__global__ __launch_bounds__(256) void transpose_v(const unsigned short* __restrict__ Vin,
                                                   unsigned short* __restrict__ VT) {
    __shared__ unsigned short T[64][72];
    const int t = threadIdx.x;
    const int s0 = blockIdx.x * 64;
    const int bh = blockIdx.y;
    const size_t ib = (size_t)bh * Sv * 64;
    const size_t ob = (size_t)bh * 64 * Sv;
    {
        const int s = t >> 2, dc = (t & 3) * 16;
        const bf16x8 a = *(const bf16x8*)&Vin[ib + (size_t)(s0 + s) * 64 + dc];
        const bf16x8 b = *(const bf16x8*)&Vin[ib + (size_t)(s0 + s) * 64 + dc + 8];
        *(bf16x8*)&T[s][dc] = a;
        *(bf16x8*)&T[s][dc + 8] = b;
    }
    __syncthreads();
    const int dv = t >> 2, sc = (t & 3) * 16;
    #pragma unroll
    for (int j4 = 0; j4 < 4; ++j4) {
        s16x4 o;
        #pragma unroll
        for (int jj = 0; jj < 4; ++jj) o[jj] = (short)T[sc + j4 * 4 + jj][dv];
        *(s16x4*)&VT[ob + (size_t)dv * Sv + s0 + sc + j4 * 4] = o;
    }
}

// ---------------------------------------------------------------------------
// bf16 MFMA GEMM: C = X[MxK](bf16) @ W + bias, weights as bf16 W^T [N][K].
// 128x128 tile, BK=32, 256 thr = 4 waves (2x2), 4x4 16x16x32 MFMA per wave.
// Both operands staged via global_load_lds width-16 (m97 structure).
// PERM=1: C bf16 -> [B,H,S,64]. PERM=0: C fp32 row-major [M,N].
// ---------------------------------------------------------------------------
template <int PERM>
__global__ __launch_bounds__(256) void gemm_mfma(const unsigned short* __restrict__ X,
                                                 const unsigned short* __restrict__ WT,
                                                 const float* __restrict__ bias,
                                                 void* __restrict__ Cv,
                                                 int M, int N, int K) {
    __shared__ short As[128 * 32];
    __shared__ short Bs[128 * 32];

    const int t = threadIdx.x;
    const int lane = t & 63, w = t >> 6;
    const int l15 = lane & 15, quad = lane >> 4;
    const int m0 = blockIdx.y * 128, n0 = blockIdx.x * 128;
    const int wm = (w >> 1) * 64, wn = (w & 1) * 64;

    f32x4 acc[4][4];
    #pragma unroll
    for (int mi = 0; mi < 4; ++mi)
        #pragma unroll
        for (int ni = 0; ni < 4; ++ni) acc[mi][ni] = (f32x4){0.f, 0.f, 0.f, 0.f};

    const int srow = lane >> 2;          // 16 rows per seg
    const int skc = (lane & 3) * 8;      // 8 bf16 = 16 B per lane

    for (int k0 = 0; k0 < K; k0 += 32) {
        #pragma unroll
        for (int i = 0; i < 2; ++i) {
            const int seg = w * 2 + i;
            const int row = seg * 16 + srow;
            glds16(&WT[(size_t)(n0 + row) * K + k0 + skc], &Bs[seg * 512]);
            glds16(&X[(size_t)(m0 + row) * K + k0 + skc], &As[seg * 512]);
        }
        __syncthreads();

        bf16x8 afr[4], bfr[4];
        #pragma unroll
        for (int mi = 0; mi < 4; ++mi)
            afr[mi] = *(const bf16x8*)&As[(wm + mi * 16 + l15) * 32 + quad * 8];
        #pragma unroll
        for (int ni = 0; ni < 4; ++ni)
            bfr[ni] = *(const bf16x8*)&Bs[(wn + ni * 16 + l15) * 32 + quad * 8];
        #pragma unroll
        for (int mi = 0; mi < 4; ++mi)
            #pragma unroll
            for (int ni = 0; ni < 4; ++ni)
                acc[mi][ni] = __builtin_amdgcn_mfma_f32_16x16x32_bf16(
                    afr[mi], bfr[ni], acc[mi][ni], 0, 0, 0);
        __syncthreads();
    }

    // Epilogue. C/D: col = l15, row = quad*4 + r.
    #pragma unroll
    for (int mi = 0; mi < 4; ++mi) {
        #pragma unroll
        for (int ni = 0; ni < 4; ++ni) {
            const int col = n0 + wn + ni * 16 + l15;
            const float bsv = bias[col];
            #pragma unroll
            for (int r = 0; r < 4; ++r) {
                const int row = m0 + wm + mi * 16 + quad * 4 + r;
                const float vv = acc[mi][ni][r] + bsv;
                if constexpr (PERM == 0) {
                    ((float*)Cv)[(size_t)row * N + col] = vv;
                } else {
                    const int bb = row / Sv, s = row % Sv;
                    const int hh = col >> 6, d = col & 63;
                    ((unsigned short*)Cv)[((((size_t)bb * Hv + hh) * Sv + s) << 6) + d] =
                        (unsigned short)f2bf(vv);
                }
            }
        }
    }
}

// ---------------------------------------------------------------------------
// Flash attention, S^T form, no-max softmax, 128-q-row tiles, 32x32x16 MFMA.
// Grid (S/128, H, B), 256 thr = 4 waves; wave w owns q-rows [w*32, w*32+32).
// QK^T: A = K (m = kk), B = Q (n = qrow). C/D (m74): col=lane&31 -> qrow,
//   row=(reg&3)+8*(reg>>2)+4*hi -> kk, i.e. st[4g+i] <-> kk = 8g+4hi+i.
// PV with OWN-KK k-step decomposition (no cross-lane exchange): the k-step's
//   (hi,elem)->kk bijection is what the lane ALREADY holds; identical maps on
//   A (P) and B (V) operands => correct for any true HW k-layout.
// Row-sums via MFMA ones-trick: lsum = mfma(P_frag, ones, lsum). The k=16
//   contraction sums BOTH hi-halves' kk and D cols are replicated, so each
//   lane's lsum[r] is exactly the row-sum for its own oacc[.][r] — no
//   shuffles, no l_acc VALU adds (work moves from 44%-busy VALU to MFMA).
// Per-32kk-block fused pipeline (R3 lesson: big live sets under a VGPR cap
//   spill; R4 lesson: __launch_bounds__ 2nd arg CAPS occupancy to N waves/EU
//   -> 24% occ; plain (256) measured 35% in R0). NO waves-per-eu arg.
// K/V tiles in LDS [64][64] bf16, XOR-swizzled (T2): byte ^= (row&7)<<4.
// T14 async-stage: next tile's K/V global-loaded into regs during compute.
// LDS = 2*8KB + 256 B = 16.6 KB -> LDS allows 9 blocks/CU; VGPR ~114 -> 4.
// ---------------------------------------------------------------------------
__global__ __launch_bounds__(256) void attn_mfma(const unsigned short* __restrict__ Q,
                                                 const unsigned short* __restrict__ Kg,
                                                 const unsigned short* __restrict__ VT,
                                                 const int* __restrict__ mask,
                                                 unsigned short* __restrict__ O) {
    __shared__ short Kl[64 * 64];    // [kk][d], swizzled
    __shared__ short Vl[64 * 64];    // [dv][kk], swizzled
    __shared__ float Mk[64];

    const int t = threadIdx.x;
    const int lane = t & 63, w = t >> 6;
    const int l31 = lane & 31, hi = lane >> 5;
    const int q0 = blockIdx.x * 128;
    const int h = blockIdx.y, b = blockIdx.z;
    const int bh = b * Hv + h;
    const size_t kvb = (size_t)bh * Sv * 64;
    const size_t vtb = (size_t)bh * 64 * Sv;
    const int fsw = (l31 & 7) << 4;          // fragment-read swizzle

    const bf16x8 ONES = {(short)0x3F80, (short)0x3F80, (short)0x3F80, (short)0x3F80,
                         (short)0x3F80, (short)0x3F80, (short)0x3F80, (short)0x3F80};

    // Q B-fragments: lane holds Q[qrow = l31][d = j*16 + hi*8 .. +8].
    bf16x8 qf[4];
    {
        const unsigned short* Qb = Q + kvb + (size_t)(q0 + w * 32 + l31) * 64;
        #pragma unroll
        for (int j = 0; j < 4; ++j) qf[j] = *(const bf16x8*)&Qb[j * 16 + hi * 8];
    }

    f32x16 oacc[2], lsum;
    #pragma unroll
    for (int d = 0; d < 2; ++d)
        #pragma unroll
        for (int i = 0; i < 16; ++i) oacc[d][i] = 0.f;
    #pragma unroll
    for (int i = 0; i < 16; ++i) lsum[i] = 0.f;

    // Staging: thread t writes row = t>>2, 2x16B at byte cols (t&3)*32 (+16),
    // XOR-swizzled by (row&7)<<4. Global source is linear.
    const int srow = t >> 2;
    const int ssw = (srow & 7) << 4;
    const int sc0 = ((t & 3) * 32) ^ ssw;
    const int sc1 = ((t & 3) * 32 + 16) ^ ssw;
    const unsigned short* Kst = Kg + kvb + (size_t)srow * 64 + (t & 3) * 16;
    const unsigned short* Vst = VT + vtb + (size_t)srow * Sv + (t & 3) * 16;
    const int* Mst = mask + (size_t)b * Sv;

    // Prologue: prefetch tile 0 into registers.
    bf16x8 kr0 = *(const bf16x8*)&Kst[0];
    bf16x8 kr1 = *(const bf16x8*)&Kst[8];
    bf16x8 vr0 = *(const bf16x8*)&Vst[0];
    bf16x8 vr1 = *(const bf16x8*)&Vst[8];
    int mreg = (t < 64) ? Mst[t] : 0;

    constexpr float CS = 0.18033688011112042f;   // 0.125 * log2(e)
    constexpr float CM = NEGV * 1.4426950408889634f;

    for (int k0 = 0; k0 < Sv; k0 += 64) {
        __syncthreads();                          // prev compute done with LDS
        *(bf16x8*)((char*)Kl + srow * 128 + sc0) = kr0;
        *(bf16x8*)((char*)Kl + srow * 128 + sc1) = kr1;
        *(bf16x8*)((char*)Vl + srow * 128 + sc0) = vr0;
        *(bf16x8*)((char*)Vl + srow * 128 + sc1) = vr1;
        if (t < 64) Mk[t] = CM * (float)mreg;
        __syncthreads();

        // T14: issue next tile's global loads now; retire during compute.
        if (k0 + 64 < Sv) {
            kr0 = *(const bf16x8*)&Kst[(size_t)(k0 + 64) * 64];
            kr1 = *(const bf16x8*)&Kst[(size_t)(k0 + 64) * 64 + 8];
            vr0 = *(const bf16x8*)&Vst[k0 + 64];
            vr1 = *(const bf16x8*)&Vst[k0 + 64 + 8];
            if (t < 64) mreg = Mst[k0 + 64 + t];
        }

        #pragma unroll
        for (int kb = 0; kb < 2; ++kb) {
            // QK^T for this 32-kk block.
            f32x16 st;
            #pragma unroll
            for (int i = 0; i < 16; ++i) st[i] = 0.f;
            #pragma unroll
            for (int j = 0; j < 4; ++j) {
                const bf16x8 kf = *(const bf16x8*)((const char*)Kl +
                    (kb * 32 + l31) * 128 + ((j * 32 + hi * 16) ^ fsw));
                st = __builtin_amdgcn_mfma_f32_32x32x16_bf16(kf, qf[j], st, 0, 0, 0);
            }
            // Softmax + own-kk pack, fused (no p[] array; st dies here).
            bf16x8 paf2[2];
            #pragma unroll
            for (int ks = 0; ks < 2; ++ks) {
                union { unsigned u[4]; bf16x8 v; } pu;
                #pragma unroll
                for (int gg = 0; gg < 2; ++gg) {
                    const int g = 2 * ks + gg;
                    const float4 mk4 = *(const float4*)&Mk[kb * 32 + 8 * g + 4 * hi];
                    const float e0 = EXP2F(__builtin_fmaf(st[4 * g + 0], CS, mk4.x));
                    const float e1 = EXP2F(__builtin_fmaf(st[4 * g + 1], CS, mk4.y));
                    const float e2 = EXP2F(__builtin_fmaf(st[4 * g + 2], CS, mk4.z));
                    const float e3 = EXP2F(__builtin_fmaf(st[4 * g + 3], CS, mk4.w));
                    pu.u[2 * gg + 0] = pkbf(e0, e1);
                    pu.u[2 * gg + 1] = pkbf(e2, e3);
                }
                paf2[ks] = pu.v;
            }
            // Row-sum via MFMA (ones-B): lsum[r] accumulates rowsum for the
            // same qrow map as oacc regs; D cols replicated -> no shuffles.
            #pragma unroll
            for (int ks = 0; ks < 2; ++ks)
                lsum = __builtin_amdgcn_mfma_f32_32x32x16_bf16(
                    paf2[ks], ONES, lsum, 0, 0, 0);
            // PV for this block's two k-steps (kk base kb*32 + ks*16).
            #pragma unroll
            for (int db = 0; db < 2; ++db) {
                const char* vrow = (const char*)Vl + (db * 32 + l31) * 128;
                #pragma unroll
                for (int ks = 0; ks < 2; ++ks) {
                    const int bofs = kb * 64 + ks * 32 + hi * 8;
                    union { s16x4 h[2]; bf16x8 v; } vu;
                    vu.h[0] = *(const s16x4*)(vrow + (bofs ^ fsw));
                    vu.h[1] = *(const s16x4*)(vrow + ((bofs + 16) ^ fsw));
                    oacc[db] = __builtin_amdgcn_mfma_f32_32x32x16_bf16(
                        paf2[ks], vu.v, oacc[db], 0, 0, 0);
                }
            }
        }
    }

    // Output: D layout col = db*32 + l31 (dv), row = (r&3) + 8*(r>>2) + 4*hi.
    // lsum[r] holds the row-sum for exactly that row — divide directly.
    f32x16 linv;
    #pragma unroll
    for (int r = 0; r < 16; ++r) linv[r] = 1.0f / lsum[r];
    #pragma unroll
    for (int db = 0; db < 2; ++db) {
        #pragma unroll
        for (int r = 0; r < 16; ++r) {
            const int rowl = (r & 3) + 8 * (r >> 2) + 4 * hi;
            const size_t row = (size_t)b * Sv + q0 + w * 32 + rowl;
            O[row * (Hv * HD) + h * HD + db * 32 + l31] =
                (unsigned short)f2bf(oacc[db][r] * linv[r]);
        }
    }
}

// ---------------------------------------------------------------------------
extern "C" void kernel_launch(void* const* d_in, const int* in_sizes, int n_in,
                              void* d_out, int out_size, void* d_ws, size_t ws_size,
                              hipStream_t stream) {
    const float* query = (const float*)d_in[0];
    const float* key   = (const float*)d_in[1];
    const float* value = (const float*)d_in[2];
    const int*   amask = (const int*)d_in[3];
    const float* wq = (const float*)d_in[4];
    const float* bq = (const float*)d_in[5];
    const float* wk = (const float*)d_in[6];
    const float* bk = (const float*)d_in[7];
    const float* wv = (const float*)d_in[8];
    const float* bv = (const float*)d_in[9];
    const float* wo = (const float*)d_in[10];
    const float* bo = (const float*)d_in[11];
    float* out = (float*)d_out;

    unsigned short* wsp = (unsigned short*)d_ws;
    dim3 bb(256), gt(16, 16);

    if (ws_size >= (size_t)64 * 1024 * 1024) {
        // ws: qb | kb | vb | ab (16 MB each, bf16 8M elems).
        const size_t PBQ = (size_t)Bv * Hv * Sv * HD;  // 8,388,608
        unsigned short* qb = wsp;
        unsigned short* kb = qb + PBQ;
        unsigned short* vb = kb + PBQ;
        unsigned short* ab = vb + PBQ;
        unsigned short* wt_kb = kb;                    // kb dead until K-GEMM
        unsigned short* wt_out = (unsigned short*)d_out;  // d_out dead until end
        unsigned short* wt_vb = vb;                    // vb dead after attn

        const int M = Bv * Sv;
        dim3 gg(8, M / 128), gc(M * 1024 / 2048);

        // V path: cvt(value)->ab ; V-GEMM ab->qb(temp) ; transpose qb->vb
        cvt_bf16<<<gc, bb, 0, stream>>>(value, ab);
        transpose_w<<<gt, bb, 0, stream>>>(wv, wt_kb);
        gemm_mfma<1><<<gg, bb, 0, stream>>>(ab, wt_kb, bv, qb, M, 1024, 1024);
        transpose_v<<<dim3(Sv / 64, Bv * Hv), bb, 0, stream>>>(qb, vb);

        // Q path (kb still dead)
        cvt_bf16<<<gc, bb, 0, stream>>>(query, ab);
        transpose_w<<<gt, bb, 0, stream>>>(wq, wt_kb);
        gemm_mfma<1><<<gg, bb, 0, stream>>>(ab, wt_kb, bq, qb, M, 1024, 1024);

        // K path (W^T scratch in d_out; kb is the GEMM target now)
        cvt_bf16<<<gc, bb, 0, stream>>>(key, ab);
        transpose_w<<<gt, bb, 0, stream>>>(wk, wt_out);
        gemm_mfma<1><<<gg, bb, 0, stream>>>(ab, wt_out, bk, kb, M, 1024, 1024);

        // Attention -> ab
        attn_mfma<<<dim3(Sv / 128, Hv, Bv), bb, 0, stream>>>(qb, kb, vb, amask, ab);

        // Output projection (W^T in dead vb; writes every element of d_out)
        transpose_w<<<gt, bb, 0, stream>>>(wo, wt_vb);
        gemm_mfma<0><<<gg, bb, 0, stream>>>(ab, wt_vb, bo, out, M, 1024, 1024);
    } else {
        // Per-batch fallback: qb|kb|vb|ab at 4 MB each = 16 MB.
        const size_t PQ = (size_t)Hv * Sv * HD;  // 2,097,152
        unsigned short* qb = wsp;
        unsigned short* kb = qb + PQ;
        unsigned short* vb = kb + PQ;
        unsigned short* ab = vb + PQ;
        const int M = Sv;
        dim3 gg(8, M / 128), gc(M * 1024 / 2048);
        for (int b = 0; b < Bv; ++b) {
            const size_t xoff = (size_t)b * Sv * Dv;
            unsigned short* wt_kb = kb;
            unsigned short* wt_out = (unsigned short*)(out + xoff);
            unsigned short* wt_vb = vb;

            cvt_bf16<<<gc, bb, 0, stream>>>(value + xoff, ab);
            transpose_w<<<gt, bb, 0, stream>>>(wv, wt_kb);
            gemm_mfma<1><<<gg, bb, 0, stream>>>(ab, wt_kb, bv, qb, M, 1024, 1024);
            transpose_v<<<dim3(Sv / 64, Hv), bb, 0, stream>>>(qb, vb);

            cvt_bf16<<<gc, bb, 0, stream>>>(query + xoff, ab);
            transpose_w<<<gt, bb, 0, stream>>>(wq, wt_kb);
            gemm_mfma<1><<<gg, bb, 0, stream>>>(ab, wt_kb, bq, qb, M, 1024, 1024);

            cvt_bf16<<<gc, bb, 0, stream>>>(key + xoff, ab);
            transpose_w<<<gt, bb, 0, stream>>>(wk, wt_out);
            gemm_mfma<1><<<gg, bb, 0, stream>>>(ab, wt_out, bk, kb, M, 1024, 1024);

            attn_mfma<<<dim3(Sv / 128, Hv, 1), bb, 0, stream>>>(qb, kb, vb,
                                                                amask + (size_t)b * Sv, ab);

            transpose_w<<<gt, bb, 0, stream>>>(wo, wt_vb);
            gemm_mfma<0><<<gg, bb, 0, stream>>>(ab, wt_vb, bo, out + xoff, M, 1024, 1024);
        }
    }
}

// Round 9
// 394.304 us; speedup vs baseline: 1.2368x; 1.0613x over previous
//
#include <hip/hip_runtime.h>
#include <hip/hip_bf16.h>
#include <math.h>

#define Bv 4
#define Sv 2048
#define Dv 1024
#define Hv 16
#define HD 64
#define NEGV (-1.0e9f)

typedef __attribute__((ext_vector_type(8))) short bf16x8;   // 8 bf16 = 16 B
typedef __attribute__((ext_vector_type(4))) short s16x4;    // 4 bf16 = 8 B
typedef __attribute__((ext_vector_type(4))) float f32x4;    // MFMA C/D

__device__ __forceinline__ short f2bf(float f) {
    union { __hip_bfloat16 h; short s; } u;
    u.h = __float2bfloat16(f);
    return u.s;
}

#if __has_builtin(__builtin_amdgcn_exp2f)
#define EXP2F(x) __builtin_amdgcn_exp2f(x)
#else
#define EXP2F(x) __expf((x) * 0.6931471805599453f)
#endif

__device__ __forceinline__ void glds16(const void* g, void* l) {
    __builtin_amdgcn_global_load_lds(
        (const __attribute__((address_space(1))) void*)g,
        (__attribute__((address_space(3))) void*)l, 16, 0, 0);
}

// ---------------------------------------------------------------------------
// fp32 -> bf16 bulk convert (FALLBACK PATH ONLY). 8 elems/thread, n /2048.
// ---------------------------------------------------------------------------
__global__ __launch_bounds__(256) void cvt_bf16(const float* __restrict__ X,
                                                unsigned short* __restrict__ Y) {
    const size_t i = ((size_t)blockIdx.x * 256 + threadIdx.x) * 8;
    const float4 a = *(const float4*)&X[i];
    const float4 b = *(const float4*)&X[i + 4];
    bf16x8 o = {f2bf(a.x), f2bf(a.y), f2bf(a.z), f2bf(a.w),
                f2bf(b.x), f2bf(b.y), f2bf(b.z), f2bf(b.w)};
    *(bf16x8*)&Y[i] = o;
}

// ---------------------------------------------------------------------------
// fp32 W [K=1024][N=1024] -> bf16 W^T [N][K]. Grid (16,16), 256 thr.
// ---------------------------------------------------------------------------
__device__ __forceinline__ void transpose_w_body(const float* __restrict__ W,
                                                 unsigned short* __restrict__ WT) {
    __shared__ float T[64][65];
    const int t = threadIdx.x;
    const int n0 = blockIdx.x * 64, k0 = blockIdx.y * 64;
    #pragma unroll
    for (int i = 0; i < 4; ++i) {
        const int k = (t >> 4) + 16 * i;
        const int nc = (t & 15) * 4;
        const float4 v = *(const float4*)&W[(size_t)(k0 + k) * 1024 + n0 + nc];
        T[k][nc + 0] = v.x; T[k][nc + 1] = v.y;
        T[k][nc + 2] = v.z; T[k][nc + 3] = v.w;
    }
    __syncthreads();
    const int n = t >> 2, kc = (t & 3) * 16;
    #pragma unroll
    for (int j4 = 0; j4 < 4; ++j4) {
        s16x4 o;
        #pragma unroll
        for (int jj = 0; jj < 4; ++jj) o[jj] = f2bf(T[kc + j4 * 4 + jj][n]);
        *(s16x4*)&WT[(size_t)(n0 + n) * 1024 + k0 + kc + j4 * 4] = o;
    }
}

__global__ __launch_bounds__(256) void transpose_w(const float* __restrict__ W,
                                                   unsigned short* __restrict__ WT) {
    transpose_w_body(W, WT);
}

// All 4 weight transposes in ONE launch. Grid (16,16,4); dst slot z.
__global__ __launch_bounds__(256) void transpose_w4(const float* __restrict__ W0,
                                                    const float* __restrict__ W1,
                                                    const float* __restrict__ W2,
                                                    const float* __restrict__ W3,
                                                    unsigned short* __restrict__ WTb) {
    const int z = blockIdx.z;
    const float* W = (z == 0) ? W0 : (z == 1) ? W1 : (z == 2) ? W2 : W3;
    transpose_w_body(W, WTb + (size_t)z * 1048576);
}

// ---------------------------------------------------------------------------
// bf16 V [BH][S][64] -> V^T [BH][64][S] (FALLBACK ONLY). Grid (S/64, nBH).
// ---------------------------------------------------------------------------
__global__ __launch_bounds__(256) void transpose_v(const unsigned short* __restrict__ Vin,
                                                   unsigned short* __restrict__ VT) {
    __shared__ unsigned short T[64][72];
    const int t = threadIdx.x;
    const int s0 = blockIdx.x * 64;
    const int bh = blockIdx.y;
    const size_t ib = (size_t)bh * Sv * 64;
    const size_t ob = (size_t)bh * 64 * Sv;
    {
        const int s = t >> 2, dc = (t & 3) * 16;
        const bf16x8 a = *(const bf16x8*)&Vin[ib + (size_t)(s0 + s) * 64 + dc];
        const bf16x8 b = *(const bf16x8*)&Vin[ib + (size_t)(s0 + s) * 64 + dc + 8];
        *(bf16x8*)&T[s][dc] = a;
        *(bf16x8*)&T[s][dc + 8] = b;
    }
    __syncthreads();
    const int dv = t >> 2, sc = (t & 3) * 16;
    #pragma unroll
    for (int j4 = 0; j4 < 4; ++j4) {
        s16x4 o;
        #pragma unroll
        for (int jj = 0; jj < 4; ++jj) o[jj] = (short)T[sc + j4 * 4 + jj][dv];
        *(s16x4*)&VT[ob + (size_t)dv * Sv + s0 + sc + j4 * 4] = o;
    }
}

// ---------------------------------------------------------------------------
// bf16 MFMA GEMM (FALLBACK): C = X(bf16) @ W + bias, W^T [N][K] bf16.
// 128x128 tile, BK=32, 4 waves, m97 structure.
// ---------------------------------------------------------------------------
template <int PERM>
__global__ __launch_bounds__(256) void gemm_mfma(const unsigned short* __restrict__ X,
                                                 const unsigned short* __restrict__ WT,
                                                 const float* __restrict__ bias,
                                                 void* __restrict__ Cv,
                                                 int M, int N, int K) {
    __shared__ short As[128 * 32];
    __shared__ short Bs[128 * 32];

    const int t = threadIdx.x;
    const int lane = t & 63, w = t >> 6;
    const int l15 = lane & 15, quad = lane >> 4;
    const int m0 = blockIdx.y * 128, n0 = blockIdx.x * 128;
    const int wm = (w >> 1) * 64, wn = (w & 1) * 64;

    f32x4 acc[4][4];
    #pragma unroll
    for (int mi = 0; mi < 4; ++mi)
        #pragma unroll
        for (int ni = 0; ni < 4; ++ni) acc[mi][ni] = (f32x4){0.f, 0.f, 0.f, 0.f};

    const int srow = lane >> 2;
    const int skc = (lane & 3) * 8;

    for (int k0 = 0; k0 < K; k0 += 32) {
        #pragma unroll
        for (int i = 0; i < 2; ++i) {
            const int seg = w * 2 + i;
            const int row = seg * 16 + srow;
            glds16(&WT[(size_t)(n0 + row) * K + k0 + skc], &Bs[seg * 512]);
            glds16(&X[(size_t)(m0 + row) * K + k0 + skc], &As[seg * 512]);
        }
        __syncthreads();

        bf16x8 afr[4], bfr[4];
        #pragma unroll
        for (int mi = 0; mi < 4; ++mi)
            afr[mi] = *(const bf16x8*)&As[(wm + mi * 16 + l15) * 32 + quad * 8];
        #pragma unroll
        for (int ni = 0; ni < 4; ++ni)
            bfr[ni] = *(const bf16x8*)&Bs[(wn + ni * 16 + l15) * 32 + quad * 8];
        #pragma unroll
        for (int mi = 0; mi < 4; ++mi)
            #pragma unroll
            for (int ni = 0; ni < 4; ++ni)
                acc[mi][ni] = __builtin_amdgcn_mfma_f32_16x16x32_bf16(
                    afr[mi], bfr[ni], acc[mi][ni], 0, 0, 0);
        __syncthreads();
    }

    #pragma unroll
    for (int mi = 0; mi < 4; ++mi) {
        #pragma unroll
        for (int ni = 0; ni < 4; ++ni) {
            const int col = n0 + wn + ni * 16 + l15;
            const float bsv = bias[col];
            #pragma unroll
            for (int r = 0; r < 4; ++r) {
                const int row = m0 + wm + mi * 16 + quad * 4 + r;
                const float vv = acc[mi][ni][r] + bsv;
                if constexpr (PERM == 0) {
                    ((float*)Cv)[(size_t)row * N + col] = vv;
                } else {
                    const int bb = row / Sv, s = row % Sv;
                    const int hh = col >> 6, d = col & 63;
                    ((unsigned short*)Cv)[((((size_t)bb * Hv + hh) * Sv + s) << 6) + d] =
                        (unsigned short)f2bf(vv);
                }
            }
        }
    }
}

// ---------------------------------------------------------------------------
// Fused Q/K/V projection GEMM. Grid (8,64,3) XCD-chunk-swizzled; z selects
// {query,key,value}. A is fp32, converted to bf16 in-register during staging
// (cvt kernel fused away); B (W^T slot z) staged via global_load_lds.
// z<2 epilogue: bf16 [B,H,S,64]. z==2: V^T [BH][64][S] directly (transpose_v
// fused away). NOTE: output params named Oq/Ok/Ov — "Dv" is a macro!
// ---------------------------------------------------------------------------
__global__ __launch_bounds__(256) void gemm_qkv(const float* __restrict__ Xq,
                                                const float* __restrict__ Xk,
                                                const float* __restrict__ Xv,
                                                const unsigned short* __restrict__ WTb,
                                                const float* __restrict__ bq,
                                                const float* __restrict__ bk,
                                                const float* __restrict__ bv,
                                                unsigned short* __restrict__ Oq,
                                                unsigned short* __restrict__ Ok,
                                                unsigned short* __restrict__ Ov) {
    __shared__ short As[128 * 32];
    __shared__ short Bs[128 * 32];

    // Bijective XCD-chunked swizzle: nwg = 1536 (%8==0).
    const int hw = blockIdx.x + 8 * (blockIdx.y + 64 * blockIdx.z);
    const int wl = (hw & 7) * 192 + (hw >> 3);
    const int bx = wl & 7, by = (wl >> 3) & 63, bz = wl >> 9;

    const float* X = (bz == 0) ? Xq : (bz == 1) ? Xk : Xv;
    const unsigned short* WT = WTb + (size_t)bz * 1048576;
    const float* bias = (bz == 0) ? bq : (bz == 1) ? bk : bv;

    const int t = threadIdx.x;
    const int lane = t & 63, w = t >> 6;
    const int l15 = lane & 15, quad = lane >> 4;
    const int m0 = by * 128, n0 = bx * 128;
    const int wm = (w >> 1) * 64, wn = (w & 1) * 64;

    f32x4 acc[4][4];
    #pragma unroll
    for (int mi = 0; mi < 4; ++mi)
        #pragma unroll
        for (int ni = 0; ni < 4; ++ni) acc[mi][ni] = (f32x4){0.f, 0.f, 0.f, 0.f};

    const int srow = lane >> 2;
    const int skc = (lane & 3) * 8;

    for (int k0 = 0; k0 < 1024; k0 += 32) {
        float4 fa[2][2];
        #pragma unroll
        for (int i = 0; i < 2; ++i) {
            const int seg = w * 2 + i;
            const int row = seg * 16 + srow;
            glds16(&WT[(size_t)(n0 + row) * 1024 + k0 + skc], &Bs[seg * 512]);
            const float* src = &X[(size_t)(m0 + row) * 1024 + k0 + skc];
            fa[i][0] = *(const float4*)src;
            fa[i][1] = *(const float4*)(src + 4);
        }
        #pragma unroll
        for (int i = 0; i < 2; ++i) {
            const int seg = w * 2 + i;
            bf16x8 o = {f2bf(fa[i][0].x), f2bf(fa[i][0].y), f2bf(fa[i][0].z), f2bf(fa[i][0].w),
                        f2bf(fa[i][1].x), f2bf(fa[i][1].y), f2bf(fa[i][1].z), f2bf(fa[i][1].w)};
            *(bf16x8*)&As[seg * 512 + lane * 8] = o;
        }
        __syncthreads();

        bf16x8 afr[4], bfr[4];
        #pragma unroll
        for (int mi = 0; mi < 4; ++mi)
            afr[mi] = *(const bf16x8*)&As[(wm + mi * 16 + l15) * 32 + quad * 8];
        #pragma unroll
        for (int ni = 0; ni < 4; ++ni)
            bfr[ni] = *(const bf16x8*)&Bs[(wn + ni * 16 + l15) * 32 + quad * 8];
        #pragma unroll
        for (int mi = 0; mi < 4; ++mi)
            #pragma unroll
            for (int ni = 0; ni < 4; ++ni)
                acc[mi][ni] = __builtin_amdgcn_mfma_f32_16x16x32_bf16(
                    afr[mi], bfr[ni], acc[mi][ni], 0, 0, 0);
        __syncthreads();
    }

    #pragma unroll
    for (int mi = 0; mi < 4; ++mi) {
        #pragma unroll
        for (int ni = 0; ni < 4; ++ni) {
            const int col = n0 + wn + ni * 16 + l15;
            const float bsv = bias[col];
            const int hh = col >> 6, d = col & 63;
            #pragma unroll
            for (int r = 0; r < 4; ++r) {
                const int row = m0 + wm + mi * 16 + quad * 4 + r;
                const int bb = row >> 11, s = row & 2047;
                const unsigned short v = (unsigned short)f2bf(acc[mi][ni][r] + bsv);
                if (bz == 2) {
                    // V^T [bh][64][S]
                    Ov[((((size_t)bb * Hv + hh) * 64 + d) << 11) + s] = v;
                } else {
                    unsigned short* O = (bz == 0) ? Oq : Ok;
                    O[((((size_t)bb * Hv + hh) * Sv + s) << 6) + d] = v;
                }
            }
        }
    }
}

// ---------------------------------------------------------------------------
// Output projection GEMM: A = attn-out bf16 in [B,H,S,64] layout, B = wo^T,
// C fp32 [M,1024]. Grid (8,64) XCD-chunk-swizzled.
// ---------------------------------------------------------------------------
__global__ __launch_bounds__(256) void gemm_out(const unsigned short* __restrict__ Xp,
                                                const unsigned short* __restrict__ WT,
                                                const float* __restrict__ bias,
                                                float* __restrict__ C) {
    __shared__ short As[128 * 32];
    __shared__ short Bs[128 * 32];

    const int hw = blockIdx.x + 8 * blockIdx.y;       // nwg = 512 (%8==0)
    const int wl = (hw & 7) * 64 + (hw >> 3);
    const int bx = wl & 7, by = wl >> 3;

    const int t = threadIdx.x;
    const int lane = t & 63, w = t >> 6;
    const int l15 = lane & 15, quad = lane >> 4;
    const int m0 = by * 128, n0 = bx * 128;
    const int wm = (w >> 1) * 64, wn = (w & 1) * 64;

    f32x4 acc[4][4];
    #pragma unroll
    for (int mi = 0; mi < 4; ++mi)
        #pragma unroll
        for (int ni = 0; ni < 4; ++ni) acc[mi][ni] = (f32x4){0.f, 0.f, 0.f, 0.f};

    const int srow = lane >> 2;
    const int skc = (lane & 3) * 8;

    for (int k0 = 0; k0 < 1024; k0 += 32) {
        const int hh = k0 >> 6, db = (k0 & 63);
        #pragma unroll
        for (int i = 0; i < 2; ++i) {
            const int seg = w * 2 + i;
            const int row = seg * 16 + srow;
            glds16(&WT[(size_t)(n0 + row) * 1024 + k0 + skc], &Bs[seg * 512]);
            const int rb = m0 + row;
            const int bb = rb >> 11, s = rb & 2047;
            glds16(&Xp[((((size_t)bb * Hv + hh) * Sv + s) << 6) + db + skc], &As[seg * 512]);
        }
        __syncthreads();

        bf16x8 afr[4], bfr[4];
        #pragma unroll
        for (int mi = 0; mi < 4; ++mi)
            afr[mi] = *(const bf16x8*)&As[(wm + mi * 16 + l15) * 32 + quad * 8];
        #pragma unroll
        for (int ni = 0; ni < 4; ++ni)
            bfr[ni] = *(const bf16x8*)&Bs[(wn + ni * 16 + l15) * 32 + quad * 8];
        #pragma unroll
        for (int mi = 0; mi < 4; ++mi)
            #pragma unroll
            for (int ni = 0; ni < 4; ++ni)
                acc[mi][ni] = __builtin_amdgcn_mfma_f32_16x16x32_bf16(
                    afr[mi], bfr[ni], acc[mi][ni], 0, 0, 0);
        __syncthreads();
    }

    #pragma unroll
    for (int mi = 0; mi < 4; ++mi) {
        #pragma unroll
        for (int ni = 0; ni < 4; ++ni) {
            const int col = n0 + wn + ni * 16 + l15;
            const float bsv = bias[col];
            #pragma unroll
            for (int r = 0; r < 4; ++r) {
                const int row = m0 + wm + mi * 16 + quad * 4 + r;
                C[(size_t)row * 1024 + col] = acc[mi][ni][r] + bsv;
            }
        }
    }
}

// ---------------------------------------------------------------------------
// Flash attention — EXACT R1 structure (empirical best: 107.9 us).
// S^T form, no-max softmax, 128-q-row tiles, 16x16x32 MFMA, Sl LDS P-relay,
// T14 reg prefetch, exp2-folded scale/mask, hoisted V fragments.
// OL=0: out [B,S,H*64] (fallback). OL=1: out [B,H,S,64] IN-PLACE into the Q
// buffer (each block writes exactly the q-rows only it reads — race-free).
// ---------------------------------------------------------------------------
template <int OL>
__global__ __launch_bounds__(256, 4) void attn_mfma(const unsigned short* __restrict__ Q,
                                                    const unsigned short* __restrict__ Kg,
                                                    const unsigned short* __restrict__ VT,
                                                    const int* __restrict__ mask,
                                                    unsigned short* __restrict__ O) {
    __shared__ short Kl[64 * 72];    // [kk][d]
    __shared__ short Vl[64 * 72];    // [dv][kk]
    __shared__ short Sl[128 * 72];   // [qrow][kk]
    __shared__ float Mk[64];

    const int t = threadIdx.x;
    const int lane = t & 63, w = t >> 6;
    const int l15 = lane & 15, quad = lane >> 4;
    const int q0 = blockIdx.x * 128;
    const int h = blockIdx.y, b = blockIdx.z;
    const int bh = b * Hv + h;
    const size_t kvb = (size_t)bh * Sv * 64;
    const size_t vtb = (size_t)bh * 64 * Sv;

    bf16x8 qf[2][2];
    #pragma unroll
    for (int ni = 0; ni < 2; ++ni) {
        const size_t qa = kvb + (size_t)(q0 + w * 32 + ni * 16 + l15) * 64 + quad * 8;
        qf[ni][0] = *(const bf16x8*)&Q[qa];
        qf[ni][1] = *(const bf16x8*)&Q[qa + 32];
    }

    float l_acc[2] = {0.f, 0.f};
    f32x4 oacc[2][4];
    #pragma unroll
    for (int mi = 0; mi < 2; ++mi)
        #pragma unroll
        for (int ni = 0; ni < 4; ++ni) oacc[mi][ni] = (f32x4){0.f, 0.f, 0.f, 0.f};

    const int srow = t >> 2, sch = (t & 3) * 16;
    const unsigned short* Kst = Kg + kvb + (size_t)srow * 64 + sch;
    const unsigned short* Vst = VT + vtb + (size_t)srow * Sv + sch;
    const int* Mst = mask + (size_t)b * Sv;

    bf16x8 kr0 = *(const bf16x8*)&Kst[0];
    bf16x8 kr1 = *(const bf16x8*)&Kst[8];
    bf16x8 vr0 = *(const bf16x8*)&Vst[0];
    bf16x8 vr1 = *(const bf16x8*)&Vst[8];
    int mreg = (t < 64) ? Mst[t] : 0;

    constexpr float CS = 0.18033688011112042f;   // 0.125 * log2(e)
    constexpr float CM = NEGV * 1.4426950408889634f;

    for (int k0 = 0; k0 < Sv; k0 += 64) {
        __syncthreads();
        *(bf16x8*)&Kl[srow * 72 + sch] = kr0;
        *(bf16x8*)&Kl[srow * 72 + sch + 8] = kr1;
        *(bf16x8*)&Vl[srow * 72 + sch] = vr0;
        *(bf16x8*)&Vl[srow * 72 + sch + 8] = vr1;
        if (t < 64) Mk[t] = CM * (float)mreg;
        __syncthreads();

        if (k0 + 64 < Sv) {
            kr0 = *(const bf16x8*)&Kst[(size_t)(k0 + 64) * 64];
            kr1 = *(const bf16x8*)&Kst[(size_t)(k0 + 64) * 64 + 8];
            vr0 = *(const bf16x8*)&Vst[k0 + 64];
            vr1 = *(const bf16x8*)&Vst[k0 + 64 + 8];
            if (t < 64) mreg = Mst[k0 + 64 + t];
        }

        #pragma unroll
        for (int mi = 0; mi < 4; ++mi) {
            const bf16x8 kf0 = *(const bf16x8*)&Kl[(mi * 16 + l15) * 72 + quad * 8];
            const bf16x8 kf1 = *(const bf16x8*)&Kl[(mi * 16 + l15) * 72 + 32 + quad * 8];
            const float4 mk4 = *(const float4*)&Mk[mi * 16 + quad * 4];
            #pragma unroll
            for (int ni = 0; ni < 2; ++ni) {
                f32x4 st = (f32x4){0.f, 0.f, 0.f, 0.f};
                st = __builtin_amdgcn_mfma_f32_16x16x32_bf16(kf0, qf[ni][0], st, 0, 0, 0);
                st = __builtin_amdgcn_mfma_f32_16x16x32_bf16(kf1, qf[ni][1], st, 0, 0, 0);
                const float p0 = EXP2F(__builtin_fmaf(st[0], CS, mk4.x));
                const float p1 = EXP2F(__builtin_fmaf(st[1], CS, mk4.y));
                const float p2 = EXP2F(__builtin_fmaf(st[2], CS, mk4.z));
                const float p3 = EXP2F(__builtin_fmaf(st[3], CS, mk4.w));
                l_acc[ni] += (p0 + p1) + (p2 + p3);
                s16x4 pv = {f2bf(p0), f2bf(p1), f2bf(p2), f2bf(p3)};
                *(s16x4*)&Sl[(w * 32 + ni * 16 + l15) * 72 + mi * 16 + quad * 4] = pv;
            }
        }

        bf16x8 vf[4][2];
        #pragma unroll
        for (int ni = 0; ni < 4; ++ni) {
            vf[ni][0] = *(const bf16x8*)&Vl[(ni * 16 + l15) * 72 + quad * 8];
            vf[ni][1] = *(const bf16x8*)&Vl[(ni * 16 + l15) * 72 + 32 + quad * 8];
        }

        #pragma unroll
        for (int mi = 0; mi < 2; ++mi) {
            const bf16x8 pf0 = *(const bf16x8*)&Sl[(w * 32 + mi * 16 + l15) * 72 + quad * 8];
            const bf16x8 pf1 = *(const bf16x8*)&Sl[(w * 32 + mi * 16 + l15) * 72 + 32 + quad * 8];
            #pragma unroll
            for (int ni = 0; ni < 4; ++ni) {
                oacc[mi][ni] = __builtin_amdgcn_mfma_f32_16x16x32_bf16(pf0, vf[ni][0], oacc[mi][ni], 0, 0, 0);
                oacc[mi][ni] = __builtin_amdgcn_mfma_f32_16x16x32_bf16(pf1, vf[ni][1], oacc[mi][ni], 0, 0, 0);
            }
        }
    }

    #pragma unroll
    for (int mi = 0; mi < 2; ++mi) {
        float l = l_acc[mi];
        l += __shfl_xor(l, 16);
        l += __shfl_xor(l, 32);
        #pragma unroll
        for (int r = 0; r < 4; ++r) {
            const float lr = __shfl(l, quad * 4 + r, 64);
            const float inv = 1.0f / lr;
            const int s = q0 + w * 32 + mi * 16 + quad * 4 + r;
            #pragma unroll
            for (int ni = 0; ni < 4; ++ni) {
                const unsigned short v = (unsigned short)f2bf(oacc[mi][ni][r] * inv);
                if constexpr (OL == 0) {
                    O[((size_t)b * Sv + s) * (Hv * HD) + h * HD + ni * 16 + l15] = v;
                } else {
                    O[kvb + ((size_t)s << 6) + ni * 16 + l15] = v;
                }
            }
        }
    }
}

// ---------------------------------------------------------------------------
extern "C" void kernel_launch(void* const* d_in, const int* in_sizes, int n_in,
                              void* d_out, int out_size, void* d_ws, size_t ws_size,
                              hipStream_t stream) {
    const float* query = (const float*)d_in[0];
    const float* key   = (const float*)d_in[1];
    const float* value = (const float*)d_in[2];
    const int*   amask = (const int*)d_in[3];
    const float* wq = (const float*)d_in[4];
    const float* bq = (const float*)d_in[5];
    const float* wk = (const float*)d_in[6];
    const float* bk = (const float*)d_in[7];
    const float* wv = (const float*)d_in[8];
    const float* bv = (const float*)d_in[9];
    const float* wo = (const float*)d_in[10];
    const float* bo = (const float*)d_in[11];
    float* out = (float*)d_out;

    unsigned short* wsp = (unsigned short*)d_ws;
    dim3 bb(256);

    if (ws_size >= (size_t)64 * 1024 * 1024) {
        // ws: qb | kb | vb | ab. qb/kb: [B,H,S,64] bf16; vb: V^T [BH][64][S];
        // ab: 4x W^T slots (wq,wk,wv,wo at z*1048576).
        const size_t PBQ = (size_t)Bv * Hv * Sv * HD;  // 8,388,608
        unsigned short* qb = wsp;
        unsigned short* kb = qb + PBQ;
        unsigned short* vb = kb + PBQ;
        unsigned short* ab = vb + PBQ;

        // 1) All 4 weight transposes, one launch.
        transpose_w4<<<dim3(16, 16, 4), bb, 0, stream>>>(wq, wk, wv, wo, ab);

        // 2) Fused QKV projections (fp32 A direct, cvt fused; V^T direct).
        gemm_qkv<<<dim3(8, 64, 3), bb, 0, stream>>>(query, key, value, ab,
                                                    bq, bk, bv, qb, kb, vb);

        // 3) Attention; output [B,H,S,64] in-place into qb.
        attn_mfma<1><<<dim3(Sv / 128, Hv, Bv), bb, 0, stream>>>(qb, kb, vb, amask, qb);

        // 4) Output projection from [B,H,S,64] layout; wo^T = ab slot 3.
        gemm_out<<<dim3(8, 64), bb, 0, stream>>>(qb, ab + (size_t)3 * 1048576, bo, out);
    } else {
        // Per-batch fallback (verified path): qb|kb|vb|ab at 4 MB each.
        const size_t PQ = (size_t)Hv * Sv * HD;  // 2,097,152
        unsigned short* qb = wsp;
        unsigned short* kb = qb + PQ;
        unsigned short* vb = kb + PQ;
        unsigned short* ab = vb + PQ;
        const int M = Sv;
        dim3 gg(8, M / 128), gc(M * 1024 / 2048), gt(16, 16);
        for (int b = 0; b < Bv; ++b) {
            const size_t xoff = (size_t)b * Sv * Dv;
            unsigned short* wt_kb = kb;
            unsigned short* wt_out = (unsigned short*)(out + xoff);
            unsigned short* wt_vb = vb;

            cvt_bf16<<<gc, bb, 0, stream>>>(value + xoff, ab);
            transpose_w<<<gt, bb, 0, stream>>>(wv, wt_kb);
            gemm_mfma<1><<<gg, bb, 0, stream>>>(ab, wt_kb, bv, qb, M, 1024, 1024);
            transpose_v<<<dim3(Sv / 64, Hv), bb, 0, stream>>>(qb, vb);

            cvt_bf16<<<gc, bb, 0, stream>>>(query + xoff, ab);
            transpose_w<<<gt, bb, 0, stream>>>(wq, wt_kb);
            gemm_mfma<1><<<gg, bb, 0, stream>>>(ab, wt_kb, bq, qb, M, 1024, 1024);

            cvt_bf16<<<gc, bb, 0, stream>>>(key + xoff, ab);
            transpose_w<<<gt, bb, 0, stream>>>(wk, wt_out);
            gemm_mfma<1><<<gg, bb, 0, stream>>>(ab, wt_out, bk, kb, M, 1024, 1024);

            attn_mfma<0><<<dim3(Sv / 128, Hv, 1), bb, 0, stream>>>(qb, kb, vb,
                                                                   amask + (size_t)b * Sv, ab);

            transpose_w<<<gt, bb, 0, stream>>>(wo, wt_vb);
            gemm_mfma<0><<<gg, bb, 0, stream>>>(ab, wt_vb, bo, out + xoff, M, 1024, 1024);
        }
    }
}

// Round 10
// 386.069 us; speedup vs baseline: 1.2632x; 1.0213x over previous
//
#include <hip/hip_runtime.h>
#include <hip/hip_bf16.h>
#include <math.h>

#define Bv 4
#define Sv 2048
#define Dv 1024
#define Hv 16
#define HD 64
#define NEGV (-1.0e9f)

typedef __attribute__((ext_vector_type(8))) short bf16x8;   // 8 bf16 = 16 B
typedef __attribute__((ext_vector_type(4))) short s16x4;    // 4 bf16 = 8 B
typedef __attribute__((ext_vector_type(4))) float f32x4;    // MFMA C/D

__device__ __forceinline__ short f2bf(float f) {
    union { __hip_bfloat16 h; short s; } u;
    u.h = __float2bfloat16(f);
    return u.s;
}

#if __has_builtin(__builtin_amdgcn_exp2f)
#define EXP2F(x) __builtin_amdgcn_exp2f(x)
#else
#define EXP2F(x) __expf((x) * 0.6931471805599453f)
#endif

__device__ __forceinline__ void glds16(const void* g, void* l) {
    __builtin_amdgcn_global_load_lds(
        (const __attribute__((address_space(1))) void*)g,
        (__attribute__((address_space(3))) void*)l, 16, 0, 0);
}

// ---------------------------------------------------------------------------
// fp32 -> bf16 bulk convert (FALLBACK PATH ONLY). 8 elems/thread, n /2048.
// ---------------------------------------------------------------------------
__global__ __launch_bounds__(256) void cvt_bf16(const float* __restrict__ X,
                                                unsigned short* __restrict__ Y) {
    const size_t i = ((size_t)blockIdx.x * 256 + threadIdx.x) * 8;
    const float4 a = *(const float4*)&X[i];
    const float4 b = *(const float4*)&X[i + 4];
    bf16x8 o = {f2bf(a.x), f2bf(a.y), f2bf(a.z), f2bf(a.w),
                f2bf(b.x), f2bf(b.y), f2bf(b.z), f2bf(b.w)};
    *(bf16x8*)&Y[i] = o;
}

// ---------------------------------------------------------------------------
// fp32 W [K=1024][N=1024] -> bf16 W^T [N][K]. Grid (16,16), 256 thr.
// ---------------------------------------------------------------------------
__device__ __forceinline__ void transpose_w_body(const float* __restrict__ W,
                                                 unsigned short* __restrict__ WT) {
    __shared__ float T[64][65];
    const int t = threadIdx.x;
    const int n0 = blockIdx.x * 64, k0 = blockIdx.y * 64;
    #pragma unroll
    for (int i = 0; i < 4; ++i) {
        const int k = (t >> 4) + 16 * i;
        const int nc = (t & 15) * 4;
        const float4 v = *(const float4*)&W[(size_t)(k0 + k) * 1024 + n0 + nc];
        T[k][nc + 0] = v.x; T[k][nc + 1] = v.y;
        T[k][nc + 2] = v.z; T[k][nc + 3] = v.w;
    }
    __syncthreads();
    const int n = t >> 2, kc = (t & 3) * 16;
    #pragma unroll
    for (int j4 = 0; j4 < 4; ++j4) {
        s16x4 o;
        #pragma unroll
        for (int jj = 0; jj < 4; ++jj) o[jj] = f2bf(T[kc + j4 * 4 + jj][n]);
        *(s16x4*)&WT[(size_t)(n0 + n) * 1024 + k0 + kc + j4 * 4] = o;
    }
}

__global__ __launch_bounds__(256) void transpose_w(const float* __restrict__ W,
                                                   unsigned short* __restrict__ WT) {
    transpose_w_body(W, WT);
}

// All 4 weight transposes in ONE launch. Grid (16,16,4); dst slot z.
__global__ __launch_bounds__(256) void transpose_w4(const float* __restrict__ W0,
                                                    const float* __restrict__ W1,
                                                    const float* __restrict__ W2,
                                                    const float* __restrict__ W3,
                                                    unsigned short* __restrict__ WTb) {
    const int z = blockIdx.z;
    const float* W = (z == 0) ? W0 : (z == 1) ? W1 : (z == 2) ? W2 : W3;
    transpose_w_body(W, WTb + (size_t)z * 1048576);
}

// ---------------------------------------------------------------------------
// bf16 V [BH][S][64] -> V^T [BH][64][S] (FALLBACK ONLY). Grid (S/64, nBH).
// ---------------------------------------------------------------------------
__global__ __launch_bounds__(256) void transpose_v(const unsigned short* __restrict__ Vin,
                                                   unsigned short* __restrict__ VT) {
    __shared__ unsigned short T[64][72];
    const int t = threadIdx.x;
    const int s0 = blockIdx.x * 64;
    const int bh = blockIdx.y;
    const size_t ib = (size_t)bh * Sv * 64;
    const size_t ob = (size_t)bh * 64 * Sv;
    {
        const int s = t >> 2, dc = (t & 3) * 16;
        const bf16x8 a = *(const bf16x8*)&Vin[ib + (size_t)(s0 + s) * 64 + dc];
        const bf16x8 b = *(const bf16x8*)&Vin[ib + (size_t)(s0 + s) * 64 + dc + 8];
        *(bf16x8*)&T[s][dc] = a;
        *(bf16x8*)&T[s][dc + 8] = b;
    }
    __syncthreads();
    const int dv = t >> 2, sc = (t & 3) * 16;
    #pragma unroll
    for (int j4 = 0; j4 < 4; ++j4) {
        s16x4 o;
        #pragma unroll
        for (int jj = 0; jj < 4; ++jj) o[jj] = (short)T[sc + j4 * 4 + jj][dv];
        *(s16x4*)&VT[ob + (size_t)dv * Sv + s0 + sc + j4 * 4] = o;
    }
}

// ---------------------------------------------------------------------------
// bf16 MFMA GEMM (FALLBACK): C = X(bf16) @ W + bias, W^T [N][K] bf16.
// 128x128 tile, BK=32, 4 waves, m97 structure.
// ---------------------------------------------------------------------------
template <int PERM>
__global__ __launch_bounds__(256) void gemm_mfma(const unsigned short* __restrict__ X,
                                                 const unsigned short* __restrict__ WT,
                                                 const float* __restrict__ bias,
                                                 void* __restrict__ Cv,
                                                 int M, int N, int K) {
    __shared__ short As[128 * 32];
    __shared__ short Bs[128 * 32];

    const int t = threadIdx.x;
    const int lane = t & 63, w = t >> 6;
    const int l15 = lane & 15, quad = lane >> 4;
    const int m0 = blockIdx.y * 128, n0 = blockIdx.x * 128;
    const int wm = (w >> 1) * 64, wn = (w & 1) * 64;

    f32x4 acc[4][4];
    #pragma unroll
    for (int mi = 0; mi < 4; ++mi)
        #pragma unroll
        for (int ni = 0; ni < 4; ++ni) acc[mi][ni] = (f32x4){0.f, 0.f, 0.f, 0.f};

    const int srow = lane >> 2;
    const int skc = (lane & 3) * 8;

    for (int k0 = 0; k0 < K; k0 += 32) {
        #pragma unroll
        for (int i = 0; i < 2; ++i) {
            const int seg = w * 2 + i;
            const int row = seg * 16 + srow;
            glds16(&WT[(size_t)(n0 + row) * K + k0 + skc], &Bs[seg * 512]);
            glds16(&X[(size_t)(m0 + row) * K + k0 + skc], &As[seg * 512]);
        }
        __syncthreads();

        bf16x8 afr[4], bfr[4];
        #pragma unroll
        for (int mi = 0; mi < 4; ++mi)
            afr[mi] = *(const bf16x8*)&As[(wm + mi * 16 + l15) * 32 + quad * 8];
        #pragma unroll
        for (int ni = 0; ni < 4; ++ni)
            bfr[ni] = *(const bf16x8*)&Bs[(wn + ni * 16 + l15) * 32 + quad * 8];
        #pragma unroll
        for (int mi = 0; mi < 4; ++mi)
            #pragma unroll
            for (int ni = 0; ni < 4; ++ni)
                acc[mi][ni] = __builtin_amdgcn_mfma_f32_16x16x32_bf16(
                    afr[mi], bfr[ni], acc[mi][ni], 0, 0, 0);
        __syncthreads();
    }

    #pragma unroll
    for (int mi = 0; mi < 4; ++mi) {
        #pragma unroll
        for (int ni = 0; ni < 4; ++ni) {
            const int col = n0 + wn + ni * 16 + l15;
            const float bsv = bias[col];
            #pragma unroll
            for (int r = 0; r < 4; ++r) {
                const int row = m0 + wm + mi * 16 + quad * 4 + r;
                const float vv = acc[mi][ni][r] + bsv;
                if constexpr (PERM == 0) {
                    ((float*)Cv)[(size_t)row * N + col] = vv;
                } else {
                    const int bb = row / Sv, s = row % Sv;
                    const int hh = col >> 6, d = col & 63;
                    ((unsigned short*)Cv)[((((size_t)bb * Hv + hh) * Sv + s) << 6) + d] =
                        (unsigned short)f2bf(vv);
                }
            }
        }
    }
}

// ---------------------------------------------------------------------------
// Fused Q/K/V projection GEMM. Grid (8,64,3) XCD-chunk-swizzled; z selects
// {query,key,value}. A is fp32 converted to bf16 in-register during staging;
// T14 async-split: the NEXT k-step's fp32 A is global-loaded into registers
// right after the staging barrier so the load retires under frag-reads+MFMA
// (R9 lesson: synchronous A staging made the kernel latency-bound —
// MfmaUtil 13%, everything idle). B staged via global_load_lds as before.
// z<2 epilogue: bf16 [B,H,S,64]. z==2: V^T [BH][64][S] directly.
// NOTE: output params named Oq/Ok/Ov — "Dv" is a macro!
// ---------------------------------------------------------------------------
__global__ __launch_bounds__(256) void gemm_qkv(const float* __restrict__ Xq,
                                                const float* __restrict__ Xk,
                                                const float* __restrict__ Xv,
                                                const unsigned short* __restrict__ WTb,
                                                const float* __restrict__ bq,
                                                const float* __restrict__ bk,
                                                const float* __restrict__ bv,
                                                unsigned short* __restrict__ Oq,
                                                unsigned short* __restrict__ Ok,
                                                unsigned short* __restrict__ Ov) {
    __shared__ short As[128 * 32];
    __shared__ short Bs[128 * 32];

    // Bijective XCD-chunked swizzle: nwg = 1536 (%8==0).
    const int hw = blockIdx.x + 8 * (blockIdx.y + 64 * blockIdx.z);
    const int wl = (hw & 7) * 192 + (hw >> 3);
    const int bx = wl & 7, by = (wl >> 3) & 63, bz = wl >> 9;

    const float* X = (bz == 0) ? Xq : (bz == 1) ? Xk : Xv;
    const unsigned short* WT = WTb + (size_t)bz * 1048576;
    const float* bias = (bz == 0) ? bq : (bz == 1) ? bk : bv;

    const int t = threadIdx.x;
    const int lane = t & 63, w = t >> 6;
    const int l15 = lane & 15, quad = lane >> 4;
    const int m0 = by * 128, n0 = bx * 128;
    const int wm = (w >> 1) * 64, wn = (w & 1) * 64;

    f32x4 acc[4][4];
    #pragma unroll
    for (int mi = 0; mi < 4; ++mi)
        #pragma unroll
        for (int ni = 0; ni < 4; ++ni) acc[mi][ni] = (f32x4){0.f, 0.f, 0.f, 0.f};

    const int srow = lane >> 2;
    const int skc = (lane & 3) * 8;

    // Per-lane A source rows (2 segs per wave).
    const float* asrc[2];
    #pragma unroll
    for (int i = 0; i < 2; ++i) {
        const int row = (w * 2 + i) * 16 + srow;
        asrc[i] = &X[(size_t)(m0 + row) * 1024 + skc];
    }

    // Prologue: prefetch k0 = 0 A-block into registers.
    float4 fa[2][2];
    #pragma unroll
    for (int i = 0; i < 2; ++i) {
        fa[i][0] = *(const float4*)(asrc[i] + 0);
        fa[i][1] = *(const float4*)(asrc[i] + 4);
    }

    for (int k0 = 0; k0 < 1024; k0 += 32) {
        // Stage: B via glds (async); A from prefetched regs (cvt + ds_write).
        #pragma unroll
        for (int i = 0; i < 2; ++i) {
            const int seg = w * 2 + i;
            const int row = seg * 16 + srow;
            glds16(&WT[(size_t)(n0 + row) * 1024 + k0 + skc], &Bs[seg * 512]);
            bf16x8 o = {f2bf(fa[i][0].x), f2bf(fa[i][0].y), f2bf(fa[i][0].z), f2bf(fa[i][0].w),
                        f2bf(fa[i][1].x), f2bf(fa[i][1].y), f2bf(fa[i][1].z), f2bf(fa[i][1].w)};
            *(bf16x8*)&As[seg * 512 + lane * 8] = o;
        }
        __syncthreads();

        // T14: issue next k-step's A loads now; retire during MFMA below.
        if (k0 + 32 < 1024) {
            #pragma unroll
            for (int i = 0; i < 2; ++i) {
                fa[i][0] = *(const float4*)(asrc[i] + k0 + 32);
                fa[i][1] = *(const float4*)(asrc[i] + k0 + 36);
            }
        }

        bf16x8 afr[4], bfr[4];
        #pragma unroll
        for (int mi = 0; mi < 4; ++mi)
            afr[mi] = *(const bf16x8*)&As[(wm + mi * 16 + l15) * 32 + quad * 8];
        #pragma unroll
        for (int ni = 0; ni < 4; ++ni)
            bfr[ni] = *(const bf16x8*)&Bs[(wn + ni * 16 + l15) * 32 + quad * 8];
        #pragma unroll
        for (int mi = 0; mi < 4; ++mi)
            #pragma unroll
            for (int ni = 0; ni < 4; ++ni)
                acc[mi][ni] = __builtin_amdgcn_mfma_f32_16x16x32_bf16(
                    afr[mi], bfr[ni], acc[mi][ni], 0, 0, 0);
        __syncthreads();
    }

    #pragma unroll
    for (int mi = 0; mi < 4; ++mi) {
        #pragma unroll
        for (int ni = 0; ni < 4; ++ni) {
            const int col = n0 + wn + ni * 16 + l15;
            const float bsv = bias[col];
            const int hh = col >> 6, d = col & 63;
            #pragma unroll
            for (int r = 0; r < 4; ++r) {
                const int row = m0 + wm + mi * 16 + quad * 4 + r;
                const int bb = row >> 11, s = row & 2047;
                const unsigned short v = (unsigned short)f2bf(acc[mi][ni][r] + bsv);
                if (bz == 2) {
                    // V^T [bh][64][S]
                    Ov[((((size_t)bb * Hv + hh) * 64 + d) << 11) + s] = v;
                } else {
                    unsigned short* O = (bz == 0) ? Oq : Ok;
                    O[((((size_t)bb * Hv + hh) * Sv + s) << 6) + d] = v;
                }
            }
        }
    }
}

// ---------------------------------------------------------------------------
// Output projection GEMM: A = attn-out bf16 in [B,H,S,64] layout, B = wo^T,
// C fp32 [M,1024]. Grid (8,64) XCD-chunk-swizzled.
// ---------------------------------------------------------------------------
__global__ __launch_bounds__(256) void gemm_out(const unsigned short* __restrict__ Xp,
                                                const unsigned short* __restrict__ WT,
                                                const float* __restrict__ bias,
                                                float* __restrict__ C) {
    __shared__ short As[128 * 32];
    __shared__ short Bs[128 * 32];

    const int hw = blockIdx.x + 8 * blockIdx.y;       // nwg = 512 (%8==0)
    const int wl = (hw & 7) * 64 + (hw >> 3);
    const int bx = wl & 7, by = wl >> 3;

    const int t = threadIdx.x;
    const int lane = t & 63, w = t >> 6;
    const int l15 = lane & 15, quad = lane >> 4;
    const int m0 = by * 128, n0 = bx * 128;
    const int wm = (w >> 1) * 64, wn = (w & 1) * 64;

    f32x4 acc[4][4];
    #pragma unroll
    for (int mi = 0; mi < 4; ++mi)
        #pragma unroll
        for (int ni = 0; ni < 4; ++ni) acc[mi][ni] = (f32x4){0.f, 0.f, 0.f, 0.f};

    const int srow = lane >> 2;
    const int skc = (lane & 3) * 8;

    for (int k0 = 0; k0 < 1024; k0 += 32) {
        const int hh = k0 >> 6, db = (k0 & 63);
        #pragma unroll
        for (int i = 0; i < 2; ++i) {
            const int seg = w * 2 + i;
            const int row = seg * 16 + srow;
            glds16(&WT[(size_t)(n0 + row) * 1024 + k0 + skc], &Bs[seg * 512]);
            const int rb = m0 + row;
            const int bb = rb >> 11, s = rb & 2047;
            glds16(&Xp[((((size_t)bb * Hv + hh) * Sv + s) << 6) + db + skc], &As[seg * 512]);
        }
        __syncthreads();

        bf16x8 afr[4], bfr[4];
        #pragma unroll
        for (int mi = 0; mi < 4; ++mi)
            afr[mi] = *(const bf16x8*)&As[(wm + mi * 16 + l15) * 32 + quad * 8];
        #pragma unroll
        for (int ni = 0; ni < 4; ++ni)
            bfr[ni] = *(const bf16x8*)&Bs[(wn + ni * 16 + l15) * 32 + quad * 8];
        #pragma unroll
        for (int mi = 0; mi < 4; ++mi)
            #pragma unroll
            for (int ni = 0; ni < 4; ++ni)
                acc[mi][ni] = __builtin_amdgcn_mfma_f32_16x16x32_bf16(
                    afr[mi], bfr[ni], acc[mi][ni], 0, 0, 0);
        __syncthreads();
    }

    #pragma unroll
    for (int mi = 0; mi < 4; ++mi) {
        #pragma unroll
        for (int ni = 0; ni < 4; ++ni) {
            const int col = n0 + wn + ni * 16 + l15;
            const float bsv = bias[col];
            #pragma unroll
            for (int r = 0; r < 4; ++r) {
                const int row = m0 + wm + mi * 16 + quad * 4 + r;
                C[(size_t)row * 1024 + col] = acc[mi][ni][r] + bsv;
            }
        }
    }
}

// ---------------------------------------------------------------------------
// Flash attention — EXACT R1 structure (empirical best: 107.9 us).
// S^T form, no-max softmax, 128-q-row tiles, 16x16x32 MFMA, Sl LDS P-relay,
// T14 reg prefetch, exp2-folded scale/mask, hoisted V fragments.
// OL=0: out [B,S,H*64] (fallback). OL=1: out [B,H,S,64] IN-PLACE into the Q
// buffer (each block writes exactly the q-rows only it reads — race-free).
// ---------------------------------------------------------------------------
template <int OL>
__global__ __launch_bounds__(256, 4) void attn_mfma(const unsigned short* __restrict__ Q,
                                                    const unsigned short* __restrict__ Kg,
                                                    const unsigned short* __restrict__ VT,
                                                    const int* __restrict__ mask,
                                                    unsigned short* __restrict__ O) {
    __shared__ short Kl[64 * 72];    // [kk][d]
    __shared__ short Vl[64 * 72];    // [dv][kk]
    __shared__ short Sl[128 * 72];   // [qrow][kk]
    __shared__ float Mk[64];

    const int t = threadIdx.x;
    const int lane = t & 63, w = t >> 6;
    const int l15 = lane & 15, quad = lane >> 4;
    const int q0 = blockIdx.x * 128;
    const int h = blockIdx.y, b = blockIdx.z;
    const int bh = b * Hv + h;
    const size_t kvb = (size_t)bh * Sv * 64;
    const size_t vtb = (size_t)bh * 64 * Sv;

    bf16x8 qf[2][2];
    #pragma unroll
    for (int ni = 0; ni < 2; ++ni) {
        const size_t qa = kvb + (size_t)(q0 + w * 32 + ni * 16 + l15) * 64 + quad * 8;
        qf[ni][0] = *(const bf16x8*)&Q[qa];
        qf[ni][1] = *(const bf16x8*)&Q[qa + 32];
    }

    float l_acc[2] = {0.f, 0.f};
    f32x4 oacc[2][4];
    #pragma unroll
    for (int mi = 0; mi < 2; ++mi)
        #pragma unroll
        for (int ni = 0; ni < 4; ++ni) oacc[mi][ni] = (f32x4){0.f, 0.f, 0.f, 0.f};

    const int srow = t >> 2, sch = (t & 3) * 16;
    const unsigned short* Kst = Kg + kvb + (size_t)srow * 64 + sch;
    const unsigned short* Vst = VT + vtb + (size_t)srow * Sv + sch;
    const int* Mst = mask + (size_t)b * Sv;

    bf16x8 kr0 = *(const bf16x8*)&Kst[0];
    bf16x8 kr1 = *(const bf16x8*)&Kst[8];
    bf16x8 vr0 = *(const bf16x8*)&Vst[0];
    bf16x8 vr1 = *(const bf16x8*)&Vst[8];
    int mreg = (t < 64) ? Mst[t] : 0;

    constexpr float CS = 0.18033688011112042f;   // 0.125 * log2(e)
    constexpr float CM = NEGV * 1.4426950408889634f;

    for (int k0 = 0; k0 < Sv; k0 += 64) {
        __syncthreads();
        *(bf16x8*)&Kl[srow * 72 + sch] = kr0;
        *(bf16x8*)&Kl[srow * 72 + sch + 8] = kr1;
        *(bf16x8*)&Vl[srow * 72 + sch] = vr0;
        *(bf16x8*)&Vl[srow * 72 + sch + 8] = vr1;
        if (t < 64) Mk[t] = CM * (float)mreg;
        __syncthreads();

        if (k0 + 64 < Sv) {
            kr0 = *(const bf16x8*)&Kst[(size_t)(k0 + 64) * 64];
            kr1 = *(const bf16x8*)&Kst[(size_t)(k0 + 64) * 64 + 8];
            vr0 = *(const bf16x8*)&Vst[k0 + 64];
            vr1 = *(const bf16x8*)&Vst[k0 + 64 + 8];
            if (t < 64) mreg = Mst[k0 + 64 + t];
        }

        #pragma unroll
        for (int mi = 0; mi < 4; ++mi) {
            const bf16x8 kf0 = *(const bf16x8*)&Kl[(mi * 16 + l15) * 72 + quad * 8];
            const bf16x8 kf1 = *(const bf16x8*)&Kl[(mi * 16 + l15) * 72 + 32 + quad * 8];
            const float4 mk4 = *(const float4*)&Mk[mi * 16 + quad * 4];
            #pragma unroll
            for (int ni = 0; ni < 2; ++ni) {
                f32x4 st = (f32x4){0.f, 0.f, 0.f, 0.f};
                st = __builtin_amdgcn_mfma_f32_16x16x32_bf16(kf0, qf[ni][0], st, 0, 0, 0);
                st = __builtin_amdgcn_mfma_f32_16x16x32_bf16(kf1, qf[ni][1], st, 0, 0, 0);
                const float p0 = EXP2F(__builtin_fmaf(st[0], CS, mk4.x));
                const float p1 = EXP2F(__builtin_fmaf(st[1], CS, mk4.y));
                const float p2 = EXP2F(__builtin_fmaf(st[2], CS, mk4.z));
                const float p3 = EXP2F(__builtin_fmaf(st[3], CS, mk4.w));
                l_acc[ni] += (p0 + p1) + (p2 + p3);
                s16x4 pv = {f2bf(p0), f2bf(p1), f2bf(p2), f2bf(p3)};
                *(s16x4*)&Sl[(w * 32 + ni * 16 + l15) * 72 + mi * 16 + quad * 4] = pv;
            }
        }

        bf16x8 vf[4][2];
        #pragma unroll
        for (int ni = 0; ni < 4; ++ni) {
            vf[ni][0] = *(const bf16x8*)&Vl[(ni * 16 + l15) * 72 + quad * 8];
            vf[ni][1] = *(const bf16x8*)&Vl[(ni * 16 + l15) * 72 + 32 + quad * 8];
        }

        #pragma unroll
        for (int mi = 0; mi < 2; ++mi) {
            const bf16x8 pf0 = *(const bf16x8*)&Sl[(w * 32 + mi * 16 + l15) * 72 + quad * 8];
            const bf16x8 pf1 = *(const bf16x8*)&Sl[(w * 32 + mi * 16 + l15) * 72 + 32 + quad * 8];
            #pragma unroll
            for (int ni = 0; ni < 4; ++ni) {
                oacc[mi][ni] = __builtin_amdgcn_mfma_f32_16x16x32_bf16(pf0, vf[ni][0], oacc[mi][ni], 0, 0, 0);
                oacc[mi][ni] = __builtin_amdgcn_mfma_f32_16x16x32_bf16(pf1, vf[ni][1], oacc[mi][ni], 0, 0, 0);
            }
        }
    }

    #pragma unroll
    for (int mi = 0; mi < 2; ++mi) {
        float l = l_acc[mi];
        l += __shfl_xor(l, 16);
        l += __shfl_xor(l, 32);
        #pragma unroll
        for (int r = 0; r < 4; ++r) {
            const float lr = __shfl(l, quad * 4 + r, 64);
            const float inv = 1.0f / lr;
            const int s = q0 + w * 32 + mi * 16 + quad * 4 + r;
            #pragma unroll
            for (int ni = 0; ni < 4; ++ni) {
                const unsigned short v = (unsigned short)f2bf(oacc[mi][ni][r] * inv);
                if constexpr (OL == 0) {
                    O[((size_t)b * Sv + s) * (Hv * HD) + h * HD + ni * 16 + l15] = v;
                } else {
                    O[kvb + ((size_t)s << 6) + ni * 16 + l15] = v;
                }
            }
        }
    }
}

// ---------------------------------------------------------------------------
extern "C" void kernel_launch(void* const* d_in, const int* in_sizes, int n_in,
                              void* d_out, int out_size, void* d_ws, size_t ws_size,
                              hipStream_t stream) {
    const float* query = (const float*)d_in[0];
    const float* key   = (const float*)d_in[1];
    const float* value = (const float*)d_in[2];
    const int*   amask = (const int*)d_in[3];
    const float* wq = (const float*)d_in[4];
    const float* bq = (const float*)d_in[5];
    const float* wk = (const float*)d_in[6];
    const float* bk = (const float*)d_in[7];
    const float* wv = (const float*)d_in[8];
    const float* bv = (const float*)d_in[9];
    const float* wo = (const float*)d_in[10];
    const float* bo = (const float*)d_in[11];
    float* out = (float*)d_out;

    unsigned short* wsp = (unsigned short*)d_ws;
    dim3 bb(256);

    if (ws_size >= (size_t)64 * 1024 * 1024) {
        // ws: qb | kb | vb | ab. qb/kb: [B,H,S,64] bf16; vb: V^T [BH][64][S];
        // ab: 4x W^T slots (wq,wk,wv,wo at z*1048576).
        const size_t PBQ = (size_t)Bv * Hv * Sv * HD;  // 8,388,608
        unsigned short* qb = wsp;
        unsigned short* kb = qb + PBQ;
        unsigned short* vb = kb + PBQ;
        unsigned short* ab = vb + PBQ;

        // 1) All 4 weight transposes, one launch.
        transpose_w4<<<dim3(16, 16, 4), bb, 0, stream>>>(wq, wk, wv, wo, ab);

        // 2) Fused QKV projections (fp32 A direct + T14 prefetch; V^T direct).
        gemm_qkv<<<dim3(8, 64, 3), bb, 0, stream>>>(query, key, value, ab,
                                                    bq, bk, bv, qb, kb, vb);

        // 3) Attention; output [B,H,S,64] in-place into qb.
        attn_mfma<1><<<dim3(Sv / 128, Hv, Bv), bb, 0, stream>>>(qb, kb, vb, amask, qb);

        // 4) Output projection from [B,H,S,64] layout; wo^T = ab slot 3.
        gemm_out<<<dim3(8, 64), bb, 0, stream>>>(qb, ab + (size_t)3 * 1048576, bo, out);
    } else {
        // Per-batch fallback (verified path): qb|kb|vb|ab at 4 MB each.
        const size_t PQ = (size_t)Hv * Sv * HD;  // 2,097,152
        unsigned short* qb = wsp;
        unsigned short* kb = qb + PQ;
        unsigned short* vb = kb + PQ;
        unsigned short* ab = vb + PQ;
        const int M = Sv;
        dim3 gg(8, M / 128), gc(M * 1024 / 2048), gt(16, 16);
        for (int b = 0; b < Bv; ++b) {
            const size_t xoff = (size_t)b * Sv * Dv;
            unsigned short* wt_kb = kb;
            unsigned short* wt_out = (unsigned short*)(out + xoff);
            unsigned short* wt_vb = vb;

            cvt_bf16<<<gc, bb, 0, stream>>>(value + xoff, ab);
            transpose_w<<<gt, bb, 0, stream>>>(wv, wt_kb);
            gemm_mfma<1><<<gg, bb, 0, stream>>>(ab, wt_kb, bv, qb, M, 1024, 1024);
            transpose_v<<<dim3(Sv / 64, Hv), bb, 0, stream>>>(qb, vb);

            cvt_bf16<<<gc, bb, 0, stream>>>(query + xoff, ab);
            transpose_w<<<gt, bb, 0, stream>>>(wq, wt_kb);
            gemm_mfma<1><<<gg, bb, 0, stream>>>(ab, wt_kb, bq, qb, M, 1024, 1024);

            cvt_bf16<<<gc, bb, 0, stream>>>(key + xoff, ab);
            transpose_w<<<gt, bb, 0, stream>>>(wk, wt_out);
            gemm_mfma<1><<<gg, bb, 0, stream>>>(ab, wt_out, bk, kb, M, 1024, 1024);

            attn_mfma<0><<<dim3(Sv / 128, Hv, 1), bb, 0, stream>>>(qb, kb, vb,
                                                                   amask + (size_t)b * Sv, ab);

            transpose_w<<<gt, bb, 0, stream>>>(wo, wt_vb);
            gemm_mfma<0><<<gg, bb, 0, stream>>>(ab, wt_vb, bo, out + xoff, M, 1024, 1024);
        }
    }
}

// Round 11
// 385.523 us; speedup vs baseline: 1.2650x; 1.0014x over previous
//
#include <hip/hip_runtime.h>
#include <hip/hip_bf16.h>
#include <math.h>

#define Bv 4
#define Sv 2048
#define Dv 1024
#define Hv 16
#define HD 64
#define NEGV (-1.0e9f)

typedef __attribute__((ext_vector_type(8))) short bf16x8;   // 8 bf16 = 16 B
typedef __attribute__((ext_vector_type(4))) short s16x4;    // 4 bf16 = 8 B
typedef __attribute__((ext_vector_type(4))) float f32x4;    // MFMA C/D

__device__ __forceinline__ short f2bf(float f) {
    union { __hip_bfloat16 h; short s; } u;
    u.h = __float2bfloat16(f);
    return u.s;
}

#if __has_builtin(__builtin_amdgcn_exp2f)
#define EXP2F(x) __builtin_amdgcn_exp2f(x)
#else
#define EXP2F(x) __expf((x) * 0.6931471805599453f)
#endif

__device__ __forceinline__ void glds16(const void* g, void* l) {
    __builtin_amdgcn_global_load_lds(
        (const __attribute__((address_space(1))) void*)g,
        (__attribute__((address_space(3))) void*)l, 16, 0, 0);
}

// ---------------------------------------------------------------------------
// fp32 -> bf16 bulk convert. 8 elems/thread. Single-tensor (fallback).
// ---------------------------------------------------------------------------
__global__ __launch_bounds__(256) void cvt_bf16(const float* __restrict__ X,
                                                unsigned short* __restrict__ Y) {
    const size_t i = ((size_t)blockIdx.x * 256 + threadIdx.x) * 8;
    const float4 a = *(const float4*)&X[i];
    const float4 b = *(const float4*)&X[i + 4];
    bf16x8 o = {f2bf(a.x), f2bf(a.y), f2bf(a.z), f2bf(a.w),
                f2bf(b.x), f2bf(b.y), f2bf(b.z), f2bf(b.w)};
    *(bf16x8*)&Y[i] = o;
}

// Multi-tensor cvt: blockIdx.y selects (x,y) pair. Grid (4096, nz).
__global__ __launch_bounds__(256) void cvt3(const float* __restrict__ x0,
                                            const float* __restrict__ x1,
                                            const float* __restrict__ x2,
                                            unsigned short* __restrict__ y0,
                                            unsigned short* __restrict__ y1,
                                            unsigned short* __restrict__ y2) {
    const int zz = blockIdx.y;
    const float* X = (zz == 0) ? x0 : (zz == 1) ? x1 : x2;
    unsigned short* Y = (zz == 0) ? y0 : (zz == 1) ? y1 : y2;
    const size_t i = ((size_t)blockIdx.x * 256 + threadIdx.x) * 8;
    const float4 a = *(const float4*)&X[i];
    const float4 b = *(const float4*)&X[i + 4];
    bf16x8 o = {f2bf(a.x), f2bf(a.y), f2bf(a.z), f2bf(a.w),
                f2bf(b.x), f2bf(b.y), f2bf(b.z), f2bf(b.w)};
    *(bf16x8*)&Y[i] = o;
}

// ---------------------------------------------------------------------------
// fp32 W [K=1024][N=1024] -> bf16 W^T [N][K]. Grid (16,16), 256 thr.
// ---------------------------------------------------------------------------
__device__ __forceinline__ void transpose_w_body(const float* __restrict__ W,
                                                 unsigned short* __restrict__ WT) {
    __shared__ float T[64][65];
    const int t = threadIdx.x;
    const int n0 = blockIdx.x * 64, k0 = blockIdx.y * 64;
    #pragma unroll
    for (int i = 0; i < 4; ++i) {
        const int k = (t >> 4) + 16 * i;
        const int nc = (t & 15) * 4;
        const float4 v = *(const float4*)&W[(size_t)(k0 + k) * 1024 + n0 + nc];
        T[k][nc + 0] = v.x; T[k][nc + 1] = v.y;
        T[k][nc + 2] = v.z; T[k][nc + 3] = v.w;
    }
    __syncthreads();
    const int n = t >> 2, kc = (t & 3) * 16;
    #pragma unroll
    for (int j4 = 0; j4 < 4; ++j4) {
        s16x4 o;
        #pragma unroll
        for (int jj = 0; jj < 4; ++jj) o[jj] = f2bf(T[kc + j4 * 4 + jj][n]);
        *(s16x4*)&WT[(size_t)(n0 + n) * 1024 + k0 + kc + j4 * 4] = o;
    }
}

__global__ __launch_bounds__(256) void transpose_w(const float* __restrict__ W,
                                                   unsigned short* __restrict__ WT) {
    transpose_w_body(W, WT);
}

// All 4 weight transposes in ONE launch. Grid (16,16,4); dst slot z.
__global__ __launch_bounds__(256) void transpose_w4(const float* __restrict__ W0,
                                                    const float* __restrict__ W1,
                                                    const float* __restrict__ W2,
                                                    const float* __restrict__ W3,
                                                    unsigned short* __restrict__ WTb) {
    const int z = blockIdx.z;
    const float* W = (z == 0) ? W0 : (z == 1) ? W1 : (z == 2) ? W2 : W3;
    transpose_w_body(W, WTb + (size_t)z * 1048576);
}

// ---------------------------------------------------------------------------
// bf16 V [BH][S][64] -> V^T [BH][64][S] (FALLBACK ONLY). Grid (S/64, nBH).
// ---------------------------------------------------------------------------
__global__ __launch_bounds__(256) void transpose_v(const unsigned short* __restrict__ Vin,
                                                   unsigned short* __restrict__ VT) {
    __shared__ unsigned short T[64][72];
    const int t = threadIdx.x;
    const int s0 = blockIdx.x * 64;
    const int bh = blockIdx.y;
    const size_t ib = (size_t)bh * Sv * 64;
    const size_t ob = (size_t)bh * 64 * Sv;
    {
        const int s = t >> 2, dc = (t & 3) * 16;
        const bf16x8 a = *(const bf16x8*)&Vin[ib + (size_t)(s0 + s) * 64 + dc];
        const bf16x8 b = *(const bf16x8*)&Vin[ib + (size_t)(s0 + s) * 64 + dc + 8];
        *(bf16x8*)&T[s][dc] = a;
        *(bf16x8*)&T[s][dc + 8] = b;
    }
    __syncthreads();
    const int dv = t >> 2, sc = (t & 3) * 16;
    #pragma unroll
    for (int j4 = 0; j4 < 4; ++j4) {
        s16x4 o;
        #pragma unroll
        for (int jj = 0; jj < 4; ++jj) o[jj] = (short)T[sc + j4 * 4 + jj][dv];
        *(s16x4*)&VT[ob + (size_t)dv * Sv + s0 + sc + j4 * 4] = o;
    }
}

// ---------------------------------------------------------------------------
// bf16 MFMA GEMM (FALLBACK): C = X(bf16) @ W + bias, W^T [N][K] bf16.
// ---------------------------------------------------------------------------
template <int PERM>
__global__ __launch_bounds__(256) void gemm_mfma(const unsigned short* __restrict__ X,
                                                 const unsigned short* __restrict__ WT,
                                                 const float* __restrict__ bias,
                                                 void* __restrict__ Cv,
                                                 int M, int N, int K) {
    __shared__ short As[128 * 32];
    __shared__ short Bs[128 * 32];

    const int t = threadIdx.x;
    const int lane = t & 63, w = t >> 6;
    const int l15 = lane & 15, quad = lane >> 4;
    const int m0 = blockIdx.y * 128, n0 = blockIdx.x * 128;
    const int wm = (w >> 1) * 64, wn = (w & 1) * 64;

    f32x4 acc[4][4];
    #pragma unroll
    for (int mi = 0; mi < 4; ++mi)
        #pragma unroll
        for (int ni = 0; ni < 4; ++ni) acc[mi][ni] = (f32x4){0.f, 0.f, 0.f, 0.f};

    const int srow = lane >> 2;
    const int skc = (lane & 3) * 8;

    for (int k0 = 0; k0 < K; k0 += 32) {
        #pragma unroll
        for (int i = 0; i < 2; ++i) {
            const int seg = w * 2 + i;
            const int row = seg * 16 + srow;
            glds16(&WT[(size_t)(n0 + row) * K + k0 + skc], &Bs[seg * 512]);
            glds16(&X[(size_t)(m0 + row) * K + k0 + skc], &As[seg * 512]);
        }
        __syncthreads();

        bf16x8 afr[4], bfr[4];
        #pragma unroll
        for (int mi = 0; mi < 4; ++mi)
            afr[mi] = *(const bf16x8*)&As[(wm + mi * 16 + l15) * 32 + quad * 8];
        #pragma unroll
        for (int ni = 0; ni < 4; ++ni)
            bfr[ni] = *(const bf16x8*)&Bs[(wn + ni * 16 + l15) * 32 + quad * 8];
        #pragma unroll
        for (int mi = 0; mi < 4; ++mi)
            #pragma unroll
            for (int ni = 0; ni < 4; ++ni)
                acc[mi][ni] = __builtin_amdgcn_mfma_f32_16x16x32_bf16(
                    afr[mi], bfr[ni], acc[mi][ni], 0, 0, 0);
        __syncthreads();
    }

    #pragma unroll
    for (int mi = 0; mi < 4; ++mi) {
        #pragma unroll
        for (int ni = 0; ni < 4; ++ni) {
            const int col = n0 + wn + ni * 16 + l15;
            const float bsv = bias[col];
            #pragma unroll
            for (int r = 0; r < 4; ++r) {
                const int row = m0 + wm + mi * 16 + quad * 4 + r;
                const float vv = acc[mi][ni][r] + bsv;
                if constexpr (PERM == 0) {
                    ((float*)Cv)[(size_t)row * N + col] = vv;
                } else {
                    const int bb = row / Sv, s = row % Sv;
                    const int hh = col >> 6, d = col & 63;
                    ((unsigned short*)Cv)[((((size_t)bb * Hv + hh) * Sv + s) << 6) + d] =
                        (unsigned short)f2bf(vv);
                }
            }
        }
    }
}

// ---------------------------------------------------------------------------
// QKV projection GEMM, bf16 A via global_load_lds (exact m97 staging — R10
// lesson: reg-staged fp32 A is latency-bound, 366 TF vs glds 874 [m151]).
// Grid (8,64,nz) XCD-chunk-swizzled (bijective: exact bit-slices).
// z list passed as za/zb/zc (actual z per raw index): 0=Q,1=K,2=V.
// z<2 epilogue: bf16 [B,H,S,64]. z==2: V^T [BH][64][S] directly.
// NOTE: identifiers must avoid macros Bv/Sv/Dv/Hv/HD/NEGV.
// ---------------------------------------------------------------------------
__global__ __launch_bounds__(256) void gemm_qkv_b(const unsigned short* __restrict__ Xq,
                                                  const unsigned short* __restrict__ Xk,
                                                  const unsigned short* __restrict__ Xv,
                                                  const unsigned short* __restrict__ WTb,
                                                  const float* __restrict__ bq,
                                                  const float* __restrict__ bk,
                                                  const float* __restrict__ bv,
                                                  unsigned short* __restrict__ Oq,
                                                  unsigned short* __restrict__ Ok,
                                                  unsigned short* __restrict__ Ov,
                                                  int za, int zb, int zc) {
    __shared__ short As[128 * 32];
    __shared__ short Bs[128 * 32];

    const int nz = gridDim.z;
    const int hw = blockIdx.x + 8 * (blockIdx.y + 64 * blockIdx.z);
    const int cpx = 64 * nz;                       // nwg/8
    const int wl = (hw & 7) * cpx + (hw >> 3);     // bijective chunk swizzle
    const int bx = wl & 7, by = (wl >> 3) & 63, bzr = wl >> 9;
    const int z = (bzr == 0) ? za : (bzr == 1) ? zb : zc;

    const unsigned short* X = (z == 0) ? Xq : (z == 1) ? Xk : Xv;
    const unsigned short* WT = WTb + (size_t)z * 1048576;
    const float* bias = (z == 0) ? bq : (z == 1) ? bk : bv;

    const int t = threadIdx.x;
    const int lane = t & 63, w = t >> 6;
    const int l15 = lane & 15, quad = lane >> 4;
    const int m0 = by * 128, n0 = bx * 128;
    const int wm = (w >> 1) * 64, wn = (w & 1) * 64;

    f32x4 acc[4][4];
    #pragma unroll
    for (int mi = 0; mi < 4; ++mi)
        #pragma unroll
        for (int ni = 0; ni < 4; ++ni) acc[mi][ni] = (f32x4){0.f, 0.f, 0.f, 0.f};

    const int srow = lane >> 2;
    const int skc = (lane & 3) * 8;

    for (int k0 = 0; k0 < 1024; k0 += 32) {
        #pragma unroll
        for (int i = 0; i < 2; ++i) {
            const int seg = w * 2 + i;
            const int row = seg * 16 + srow;
            glds16(&WT[(size_t)(n0 + row) * 1024 + k0 + skc], &Bs[seg * 512]);
            glds16(&X[(size_t)(m0 + row) * 1024 + k0 + skc], &As[seg * 512]);
        }
        __syncthreads();

        bf16x8 afr[4], bfr[4];
        #pragma unroll
        for (int mi = 0; mi < 4; ++mi)
            afr[mi] = *(const bf16x8*)&As[(wm + mi * 16 + l15) * 32 + quad * 8];
        #pragma unroll
        for (int ni = 0; ni < 4; ++ni)
            bfr[ni] = *(const bf16x8*)&Bs[(wn + ni * 16 + l15) * 32 + quad * 8];
        #pragma unroll
        for (int mi = 0; mi < 4; ++mi)
            #pragma unroll
            for (int ni = 0; ni < 4; ++ni)
                acc[mi][ni] = __builtin_amdgcn_mfma_f32_16x16x32_bf16(
                    afr[mi], bfr[ni], acc[mi][ni], 0, 0, 0);
        __syncthreads();
    }

    #pragma unroll
    for (int mi = 0; mi < 4; ++mi) {
        #pragma unroll
        for (int ni = 0; ni < 4; ++ni) {
            const int col = n0 + wn + ni * 16 + l15;
            const float bsv = bias[col];
            const int hh = col >> 6, d = col & 63;
            #pragma unroll
            for (int r = 0; r < 4; ++r) {
                const int row = m0 + wm + mi * 16 + quad * 4 + r;
                const int bb = row >> 11, s = row & 2047;
                const unsigned short v = (unsigned short)f2bf(acc[mi][ni][r] + bsv);
                if (z == 2) {
                    Ov[((((size_t)bb * Hv + hh) * 64 + d) << 11) + s] = v;   // V^T
                } else {
                    unsigned short* Od = (z == 0) ? Oq : Ok;
                    Od[((((size_t)bb * Hv + hh) * Sv + s) << 6) + d] = v;
                }
            }
        }
    }
}

// ---------------------------------------------------------------------------
// Output projection GEMM: A = attn-out bf16 in [B,H,S,64] layout, B = wo^T,
// C fp32 [M,1024]. Grid (8,64) XCD-chunk-swizzled.
// ---------------------------------------------------------------------------
__global__ __launch_bounds__(256) void gemm_out(const unsigned short* __restrict__ Xp,
                                                const unsigned short* __restrict__ WT,
                                                const float* __restrict__ bias,
                                                float* __restrict__ C) {
    __shared__ short As[128 * 32];
    __shared__ short Bs[128 * 32];

    const int hw = blockIdx.x + 8 * blockIdx.y;       // nwg = 512 (%8==0)
    const int wl = (hw & 7) * 64 + (hw >> 3);
    const int bx = wl & 7, by = wl >> 3;

    const int t = threadIdx.x;
    const int lane = t & 63, w = t >> 6;
    const int l15 = lane & 15, quad = lane >> 4;
    const int m0 = by * 128, n0 = bx * 128;
    const int wm = (w >> 1) * 64, wn = (w & 1) * 64;

    f32x4 acc[4][4];
    #pragma unroll
    for (int mi = 0; mi < 4; ++mi)
        #pragma unroll
        for (int ni = 0; ni < 4; ++ni) acc[mi][ni] = (f32x4){0.f, 0.f, 0.f, 0.f};

    const int srow = lane >> 2;
    const int skc = (lane & 3) * 8;

    for (int k0 = 0; k0 < 1024; k0 += 32) {
        const int hh = k0 >> 6, db = (k0 & 63);
        #pragma unroll
        for (int i = 0; i < 2; ++i) {
            const int seg = w * 2 + i;
            const int row = seg * 16 + srow;
            glds16(&WT[(size_t)(n0 + row) * 1024 + k0 + skc], &Bs[seg * 512]);
            const int rb = m0 + row;
            const int bb = rb >> 11, s = rb & 2047;
            glds16(&Xp[((((size_t)bb * Hv + hh) * Sv + s) << 6) + db + skc], &As[seg * 512]);
        }
        __syncthreads();

        bf16x8 afr[4], bfr[4];
        #pragma unroll
        for (int mi = 0; mi < 4; ++mi)
            afr[mi] = *(const bf16x8*)&As[(wm + mi * 16 + l15) * 32 + quad * 8];
        #pragma unroll
        for (int ni = 0; ni < 4; ++ni)
            bfr[ni] = *(const bf16x8*)&Bs[(wn + ni * 16 + l15) * 32 + quad * 8];
        #pragma unroll
        for (int mi = 0; mi < 4; ++mi)
            #pragma unroll
            for (int ni = 0; ni < 4; ++ni)
                acc[mi][ni] = __builtin_amdgcn_mfma_f32_16x16x32_bf16(
                    afr[mi], bfr[ni], acc[mi][ni], 0, 0, 0);
        __syncthreads();
    }

    #pragma unroll
    for (int mi = 0; mi < 4; ++mi) {
        #pragma unroll
        for (int ni = 0; ni < 4; ++ni) {
            const int col = n0 + wn + ni * 16 + l15;
            const float bsv = bias[col];
            #pragma unroll
            for (int r = 0; r < 4; ++r) {
                const int row = m0 + wm + mi * 16 + quad * 4 + r;
                C[(size_t)row * 1024 + col] = acc[mi][ni][r] + bsv;
            }
        }
    }
}

// ---------------------------------------------------------------------------
// Flash attention — EXACT R1 structure (empirical best: 107.9 us).
// OL=0: out [B,S,H*64] (fallback). OL=1: out [B,H,S,64] IN-PLACE into Q buf.
// ---------------------------------------------------------------------------
template <int OL>
__global__ __launch_bounds__(256, 4) void attn_mfma(const unsigned short* __restrict__ Q,
                                                    const unsigned short* __restrict__ Kg,
                                                    const unsigned short* __restrict__ VT,
                                                    const int* __restrict__ mask,
                                                    unsigned short* __restrict__ O) {
    __shared__ short Kl[64 * 72];    // [kk][d]
    __shared__ short Vl[64 * 72];    // [dv][kk]
    __shared__ short Sl[128 * 72];   // [qrow][kk]
    __shared__ float Mk[64];

    const int t = threadIdx.x;
    const int lane = t & 63, w = t >> 6;
    const int l15 = lane & 15, quad = lane >> 4;
    const int q0 = blockIdx.x * 128;
    const int h = blockIdx.y, b = blockIdx.z;
    const int bh = b * Hv + h;
    const size_t kvb = (size_t)bh * Sv * 64;
    const size_t vtb = (size_t)bh * 64 * Sv;

    bf16x8 qf[2][2];
    #pragma unroll
    for (int ni = 0; ni < 2; ++ni) {
        const size_t qa = kvb + (size_t)(q0 + w * 32 + ni * 16 + l15) * 64 + quad * 8;
        qf[ni][0] = *(const bf16x8*)&Q[qa];
        qf[ni][1] = *(const bf16x8*)&Q[qa + 32];
    }

    float l_acc[2] = {0.f, 0.f};
    f32x4 oacc[2][4];
    #pragma unroll
    for (int mi = 0; mi < 2; ++mi)
        #pragma unroll
        for (int ni = 0; ni < 4; ++ni) oacc[mi][ni] = (f32x4){0.f, 0.f, 0.f, 0.f};

    const int srow = t >> 2, sch = (t & 3) * 16;
    const unsigned short* Kst = Kg + kvb + (size_t)srow * 64 + sch;
    const unsigned short* Vst = VT + vtb + (size_t)srow * Sv + sch;
    const int* Mst = mask + (size_t)b * Sv;

    bf16x8 kr0 = *(const bf16x8*)&Kst[0];
    bf16x8 kr1 = *(const bf16x8*)&Kst[8];
    bf16x8 vr0 = *(const bf16x8*)&Vst[0];
    bf16x8 vr1 = *(const bf16x8*)&Vst[8];
    int mreg = (t < 64) ? Mst[t] : 0;

    constexpr float CS = 0.18033688011112042f;   // 0.125 * log2(e)
    constexpr float CM = NEGV * 1.4426950408889634f;

    for (int k0 = 0; k0 < Sv; k0 += 64) {
        __syncthreads();
        *(bf16x8*)&Kl[srow * 72 + sch] = kr0;
        *(bf16x8*)&Kl[srow * 72 + sch + 8] = kr1;
        *(bf16x8*)&Vl[srow * 72 + sch] = vr0;
        *(bf16x8*)&Vl[srow * 72 + sch + 8] = vr1;
        if (t < 64) Mk[t] = CM * (float)mreg;
        __syncthreads();

        if (k0 + 64 < Sv) {
            kr0 = *(const bf16x8*)&Kst[(size_t)(k0 + 64) * 64];
            kr1 = *(const bf16x8*)&Kst[(size_t)(k0 + 64) * 64 + 8];
            vr0 = *(const bf16x8*)&Vst[k0 + 64];
            vr1 = *(const bf16x8*)&Vst[k0 + 64 + 8];
            if (t < 64) mreg = Mst[k0 + 64 + t];
        }

        #pragma unroll
        for (int mi = 0; mi < 4; ++mi) {
            const bf16x8 kf0 = *(const bf16x8*)&Kl[(mi * 16 + l15) * 72 + quad * 8];
            const bf16x8 kf1 = *(const bf16x8*)&Kl[(mi * 16 + l15) * 72 + 32 + quad * 8];
            const float4 mk4 = *(const float4*)&Mk[mi * 16 + quad * 4];
            #pragma unroll
            for (int ni = 0; ni < 2; ++ni) {
                f32x4 st = (f32x4){0.f, 0.f, 0.f, 0.f};
                st = __builtin_amdgcn_mfma_f32_16x16x32_bf16(kf0, qf[ni][0], st, 0, 0, 0);
                st = __builtin_amdgcn_mfma_f32_16x16x32_bf16(kf1, qf[ni][1], st, 0, 0, 0);
                const float p0 = EXP2F(__builtin_fmaf(st[0], CS, mk4.x));
                const float p1 = EXP2F(__builtin_fmaf(st[1], CS, mk4.y));
                const float p2 = EXP2F(__builtin_fmaf(st[2], CS, mk4.z));
                const float p3 = EXP2F(__builtin_fmaf(st[3], CS, mk4.w));
                l_acc[ni] += (p0 + p1) + (p2 + p3);
                s16x4 pv = {f2bf(p0), f2bf(p1), f2bf(p2), f2bf(p3)};
                *(s16x4*)&Sl[(w * 32 + ni * 16 + l15) * 72 + mi * 16 + quad * 4] = pv;
            }
        }

        bf16x8 vf[4][2];
        #pragma unroll
        for (int ni = 0; ni < 4; ++ni) {
            vf[ni][0] = *(const bf16x8*)&Vl[(ni * 16 + l15) * 72 + quad * 8];
            vf[ni][1] = *(const bf16x8*)&Vl[(ni * 16 + l15) * 72 + 32 + quad * 8];
        }

        #pragma unroll
        for (int mi = 0; mi < 2; ++mi) {
            const bf16x8 pf0 = *(const bf16x8*)&Sl[(w * 32 + mi * 16 + l15) * 72 + quad * 8];
            const bf16x8 pf1 = *(const bf16x8*)&Sl[(w * 32 + mi * 16 + l15) * 72 + 32 + quad * 8];
            #pragma unroll
            for (int ni = 0; ni < 4; ++ni) {
                oacc[mi][ni] = __builtin_amdgcn_mfma_f32_16x16x32_bf16(pf0, vf[ni][0], oacc[mi][ni], 0, 0, 0);
                oacc[mi][ni] = __builtin_amdgcn_mfma_f32_16x16x32_bf16(pf1, vf[ni][1], oacc[mi][ni], 0, 0, 0);
            }
        }
    }

    #pragma unroll
    for (int mi = 0; mi < 2; ++mi) {
        float l = l_acc[mi];
        l += __shfl_xor(l, 16);
        l += __shfl_xor(l, 32);
        #pragma unroll
        for (int r = 0; r < 4; ++r) {
            const float lr = __shfl(l, quad * 4 + r, 64);
            const float inv = 1.0f / lr;
            const int s = q0 + w * 32 + mi * 16 + quad * 4 + r;
            #pragma unroll
            for (int ni = 0; ni < 4; ++ni) {
                const unsigned short v = (unsigned short)f2bf(oacc[mi][ni][r] * inv);
                if constexpr (OL == 0) {
                    O[((size_t)b * Sv + s) * (Hv * HD) + h * HD + ni * 16 + l15] = v;
                } else {
                    O[kvb + ((size_t)s << 6) + ni * 16 + l15] = v;
                }
            }
        }
    }
}

// ---------------------------------------------------------------------------
extern "C" void kernel_launch(void* const* d_in, const int* in_sizes, int n_in,
                              void* d_out, int out_size, void* d_ws, size_t ws_size,
                              hipStream_t stream) {
    const float* query = (const float*)d_in[0];
    const float* key   = (const float*)d_in[1];
    const float* value = (const float*)d_in[2];
    const int*   amask = (const int*)d_in[3];
    const float* wq = (const float*)d_in[4];
    const float* bq = (const float*)d_in[5];
    const float* wk = (const float*)d_in[6];
    const float* bk = (const float*)d_in[7];
    const float* wv = (const float*)d_in[8];
    const float* bv = (const float*)d_in[9];
    const float* wo = (const float*)d_in[10];
    const float* bo = (const float*)d_in[11];
    float* out = (float*)d_out;

    unsigned short* wsp = (unsigned short*)d_ws;
    dim3 bb(256);
    const size_t PBQ = (size_t)Bv * Hv * Sv * HD;  // 8,388,608 bf16 = 16 MB

    if (ws_size >= (size_t)112 * 1024 * 1024) {
        // ws: qb | kb | vb | ab | xb0 | xb1 | xb2  (7 x 16 MB)
        unsigned short* qb = wsp;
        unsigned short* kb = qb + PBQ;
        unsigned short* vb = kb + PBQ;
        unsigned short* ab = vb + PBQ;
        unsigned short* xb0 = ab + PBQ;
        unsigned short* xb1 = xb0 + PBQ;
        unsigned short* xb2 = xb1 + PBQ;

        transpose_w4<<<dim3(16, 16, 4), bb, 0, stream>>>(wq, wk, wv, wo, ab);
        cvt3<<<dim3(4096, 3), bb, 0, stream>>>(query, key, value, xb0, xb1, xb2);
        gemm_qkv_b<<<dim3(8, 64, 3), bb, 0, stream>>>(xb0, xb1, xb2, ab,
                                                      bq, bk, bv, qb, kb, vb, 0, 1, 2);
        attn_mfma<1><<<dim3(Sv / 128, Hv, Bv), bb, 0, stream>>>(qb, kb, vb, amask, qb);
        gemm_out<<<dim3(8, 64), bb, 0, stream>>>(qb, ab + (size_t)3 * 1048576, bo, out);
    } else if (ws_size >= (size_t)64 * 1024 * 1024) {
        // ws: qb | kb | vb | ab. bf16 activation scratch lives in dead d_out
        // (32 MB = 2 slots); K's activation staged after QV GEMM frees slot 0.
        unsigned short* qb = wsp;
        unsigned short* kb = qb + PBQ;
        unsigned short* vb = kb + PBQ;
        unsigned short* ab = vb + PBQ;
        unsigned short* dout_s = (unsigned short*)d_out;
        unsigned short* xv = dout_s;            // slot 0
        unsigned short* xq = dout_s + PBQ;      // slot 1
        unsigned short* xk = dout_s;            // slot 0 (reused)

        transpose_w4<<<dim3(16, 16, 4), bb, 0, stream>>>(wq, wk, wv, wo, ab);
        // cvt value->xv, query->xq (one launch, 2 z-slices)
        cvt3<<<dim3(4096, 2), bb, 0, stream>>>(value, query, query, xv, xq, xq);
        // V-proj (z=2, A=xv) -> vb ; Q-proj (z=0, A=xq) -> qb
        gemm_qkv_b<<<dim3(8, 64, 2), bb, 0, stream>>>(xq, xq, xv, ab,
                                                      bq, bk, bv, qb, kb, vb, 2, 0, 0);
        // cvt key -> xk (slot 0 now dead)
        cvt3<<<dim3(4096, 1), bb, 0, stream>>>(key, key, key, xk, xk, xk);
        // K-proj (z=1, A=xk) -> kb
        gemm_qkv_b<<<dim3(8, 64, 1), bb, 0, stream>>>(xk, xk, xk, ab,
                                                      bq, bk, bv, qb, kb, vb, 1, 1, 1);
        // Attention; output [B,H,S,64] in-place into qb.
        attn_mfma<1><<<dim3(Sv / 128, Hv, Bv), bb, 0, stream>>>(qb, kb, vb, amask, qb);
        // Output projection (overwrites all of d_out; reads only qb/ab).
        gemm_out<<<dim3(8, 64), bb, 0, stream>>>(qb, ab + (size_t)3 * 1048576, bo, out);
    } else {
        // Per-batch fallback (verified path): qb|kb|vb|ab at 4 MB each.
        const size_t PQ = (size_t)Hv * Sv * HD;  // 2,097,152
        unsigned short* qb = wsp;
        unsigned short* kb = qb + PQ;
        unsigned short* vb = kb + PQ;
        unsigned short* ab = vb + PQ;
        const int M = Sv;
        dim3 gg(8, M / 128), gc(M * 1024 / 2048), gt(16, 16);
        for (int b = 0; b < Bv; ++b) {
            const size_t xoff = (size_t)b * Sv * Dv;
            unsigned short* wt_kb = kb;
            unsigned short* wt_out = (unsigned short*)(out + xoff);
            unsigned short* wt_vb = vb;

            cvt_bf16<<<gc, bb, 0, stream>>>(value + xoff, ab);
            transpose_w<<<gt, bb, 0, stream>>>(wv, wt_kb);
            gemm_mfma<1><<<gg, bb, 0, stream>>>(ab, wt_kb, bv, qb, M, 1024, 1024);
            transpose_v<<<dim3(Sv / 64, Hv), bb, 0, stream>>>(qb, vb);

            cvt_bf16<<<gc, bb, 0, stream>>>(query + xoff, ab);
            transpose_w<<<gt, bb, 0, stream>>>(wq, wt_kb);
            gemm_mfma<1><<<gg, bb, 0, stream>>>(ab, wt_kb, bq, qb, M, 1024, 1024);

            cvt_bf16<<<gc, bb, 0, stream>>>(key + xoff, ab);
            transpose_w<<<gt, bb, 0, stream>>>(wk, wt_out);
            gemm_mfma<1><<<gg, bb, 0, stream>>>(ab, wt_out, bk, kb, M, 1024, 1024);

            attn_mfma<0><<<dim3(Sv / 128, Hv, 1), bb, 0, stream>>>(qb, kb, vb,
                                                                   amask + (size_t)b * Sv, ab);

            transpose_w<<<gt, bb, 0, stream>>>(wo, wt_vb);
            gemm_mfma<0><<<gg, bb, 0, stream>>>(ab, wt_vb, bo, out + xoff, M, 1024, 1024);
        }
    }
}